// Round 1
// 3290.578 us; speedup vs baseline: 10.0962x; 10.0962x over previous
//
#include <hip/hip_runtime.h>
#include <stdint.h>
#include <stddef.h>

// ---------------- problem constants ----------------
static constexpr int N    = 100000;
static constexpr int HID  = 256;
static constexpr int IEMB = 128;
static constexpr int NNZ  = 3200000;
static constexpr int OUTW = 3 * HID + IEMB;  // 896
static constexpr float NEG_SLOPE = 0.2f;

// JAX threefry variant: 1 = partitionable (default in JAX >= 0.5.0), 0 = original
#define THREEFRY_PARTITIONABLE 1

// ---------------- threefry2x32 (JAX-compatible) ----------------
__host__ __device__ inline uint32_t rotl32(uint32_t v, int r) {
  return (v << r) | (v >> (32 - r));
}

__host__ __device__ inline void threefry2x32(uint32_t k0, uint32_t k1,
                                             uint32_t x0, uint32_t x1,
                                             uint32_t& o0, uint32_t& o1) {
  const uint32_t k2 = k0 ^ k1 ^ 0x1BD11BDAu;
  x0 += k0; x1 += k1;
  // rounds 1-4
  x0 += x1; x1 = rotl32(x1, 13); x1 ^= x0;
  x0 += x1; x1 = rotl32(x1, 15); x1 ^= x0;
  x0 += x1; x1 = rotl32(x1, 26); x1 ^= x0;
  x0 += x1; x1 = rotl32(x1,  6); x1 ^= x0;
  x0 += k1; x1 += k2 + 1u;
  // rounds 5-8
  x0 += x1; x1 = rotl32(x1, 17); x1 ^= x0;
  x0 += x1; x1 = rotl32(x1, 29); x1 ^= x0;
  x0 += x1; x1 = rotl32(x1, 16); x1 ^= x0;
  x0 += x1; x1 = rotl32(x1, 24); x1 ^= x0;
  x0 += k2; x1 += k0 + 2u;
  // rounds 9-12
  x0 += x1; x1 = rotl32(x1, 13); x1 ^= x0;
  x0 += x1; x1 = rotl32(x1, 15); x1 ^= x0;
  x0 += x1; x1 = rotl32(x1, 26); x1 ^= x0;
  x0 += x1; x1 = rotl32(x1,  6); x1 ^= x0;
  x0 += k0; x1 += k1 + 3u;
  // rounds 13-16
  x0 += x1; x1 = rotl32(x1, 17); x1 ^= x0;
  x0 += x1; x1 = rotl32(x1, 29); x1 ^= x0;
  x0 += x1; x1 = rotl32(x1, 16); x1 ^= x0;
  x0 += x1; x1 = rotl32(x1, 24); x1 ^= x0;
  x0 += k1; x1 += k2 + 4u;
  // rounds 17-20
  x0 += x1; x1 = rotl32(x1, 13); x1 ^= x0;
  x0 += x1; x1 = rotl32(x1, 15); x1 ^= x0;
  x0 += x1; x1 = rotl32(x1, 26); x1 ^= x0;
  x0 += x1; x1 = rotl32(x1,  6); x1 ^= x0;
  x0 += k2; x1 += k0 + 5u;
  o0 = x0; o1 = x1;
}

// keep-mask for flat element index e of a [N,HID] dropout draw under key (k0,k1)
__device__ inline bool keep_elem(uint32_t k0, uint32_t k1, uint32_t e) {
  uint32_t o0, o1, bits;
#if THREEFRY_PARTITIONABLE
  threefry2x32(k0, k1, 0u, e, o0, o1);   // counter = 64-bit flat index (hi=0, lo=e)
  bits = o0 ^ o1;                        // 32-bit draw folds the two output words
#else
  const uint32_t H = (uint32_t)(N) * (uint32_t)(HID) / 2u;  // 12,800,000
  if (e < H) { threefry2x32(k0, k1, e, e + H, o0, o1); bits = o0; }
  else       { threefry2x32(k0, k1, e - H, e, o0, o1); bits = o1; }
#endif
  float u = __uint_as_float((bits >> 9) | 0x3f800000u) - 1.0f;  // [0,1)
  return u < 0.9f;  // bernoulli(keep=0.9): uniform < p
}

// ---------------- kernels (all float32) ----------------

// x = embed[x_idx]; write f32 copy to A (stride HID) and to out cols [0,256)
__global__ __launch_bounds__(256) void k_gather(const int* __restrict__ xidx,
                                                const float* __restrict__ emb,
                                                float* __restrict__ A,
                                                float* __restrict__ out) {
  int t = blockIdx.x * 256 + threadIdx.x;          // over N*64 chunks of 4 elems
  int n = t >> 6;
  int c4 = (t & 63) * 4;
  if (n >= N) return;
  int src = xidx[n];
  float4 v = *(const float4*)(emb + (size_t)src * HID + c4);
  *(float4*)(out + (size_t)n * OUTW + c4) = v;
  *(float4*)(A + (size_t)n * HID + c4) = v;
}

__global__ __launch_bounds__(256) void k_zero(float4* __restrict__ p, int n4) {
  int i = blockIdx.x * 256 + threadIdx.x;
  if (i < n4) p[i] = make_float4(0.f, 0.f, 0.f, 0.f);
}

__global__ __launch_bounds__(256) void k_zero_i(int* __restrict__ p, int n) {
  int i = blockIdx.x * 256 + threadIdx.x;
  if (i < n) p[i] = 0;
}

// ---- CSR build: histogram -> single-block scan -> scatter (col,val) pairs ----

__global__ __launch_bounds__(256) void k_hist(const int* __restrict__ rows,
                                              int* __restrict__ RO) {
  int e = blockIdx.x * 256 + threadIdx.x;
  if (e < NNZ) atomicAdd(&RO[rows[e]], 1);
}

// RO[0..N-1] holds counts on entry. On exit: RO[0..N] = exclusive scan (RO[N]=NNZ),
// C[r] = RO[r] (scatter cursors). Single block of 256 threads.
__global__ __launch_bounds__(256) void k_scan(int* __restrict__ RO, int* __restrict__ C) {
  __shared__ int part[256];
  const int T = 256;
  const int K = (N + T - 1) / T;  // 391
  int t = threadIdx.x;
  int lo = t * K;
  int hi = lo + K; if (hi > N) hi = N;
  int s = 0;
  for (int i = lo; i < hi; ++i) s += RO[i];
  part[t] = s;
  __syncthreads();
  if (t == 0) {
    int run = 0;
    for (int i = 0; i < T; ++i) { int v = part[i]; part[i] = run; run += v; }
  }
  __syncthreads();
  int run = part[t];
  for (int i = lo; i < hi; ++i) {
    int v = RO[i];
    RO[i] = run;
    C[i]  = run;
    run += v;
  }
  if (t == T - 1) RO[N] = run;  // == NNZ
}

__global__ __launch_bounds__(256) void k_scatter(const int* __restrict__ rows,
                                                 const int* __restrict__ cols,
                                                 const float* __restrict__ vals,
                                                 int* __restrict__ C,
                                                 int2* __restrict__ CV) {
  int e = blockIdx.x * 256 + threadIdx.x;
  if (e >= NNZ) return;
  int r = rows[e];
  int pos = atomicAdd(&C[r], 1);
  CV[pos] = make_int2(cols[e], __float_as_int(vals[e]));
}

// Row-parallel CSR SpMM, fused residual + dropout:
// B[r] = dropout(sum_e v_e * A[col_e] + A[r]).
// One wave per row: 64 lanes x float4 = full 256-wide row in registers. No atomics.
__global__ __launch_bounds__(256) void k_spmm_csr(const int* __restrict__ RO,
                                                  const int2* __restrict__ CV,
                                                  const float* __restrict__ A,
                                                  float* __restrict__ B,
                                                  uint32_t k0, uint32_t k1) {
  int r = blockIdx.x * 4 + (threadIdx.x >> 6);
  if (r >= N) return;
  int c4 = (threadIdx.x & 63) * 4;
  int beg = RO[r], end = RO[r + 1];

  float ax = 0.f, ay = 0.f, az = 0.f, aw = 0.f;
  int i = beg;
  // 4-way unrolled edge loop: 4 independent gathers in flight per iteration
  for (; i + 3 < end; i += 4) {
    int2 cv0 = CV[i + 0], cv1 = CV[i + 1], cv2 = CV[i + 2], cv3 = CV[i + 3];
    float4 x0 = *(const float4*)(A + (size_t)cv0.x * HID + c4);
    float4 x1 = *(const float4*)(A + (size_t)cv1.x * HID + c4);
    float4 x2 = *(const float4*)(A + (size_t)cv2.x * HID + c4);
    float4 x3 = *(const float4*)(A + (size_t)cv3.x * HID + c4);
    float v0 = __int_as_float(cv0.y), v1 = __int_as_float(cv1.y);
    float v2 = __int_as_float(cv2.y), v3 = __int_as_float(cv3.y);
    ax = fmaf(v0, x0.x, ax); ay = fmaf(v0, x0.y, ay);
    az = fmaf(v0, x0.z, az); aw = fmaf(v0, x0.w, aw);
    ax = fmaf(v1, x1.x, ax); ay = fmaf(v1, x1.y, ay);
    az = fmaf(v1, x1.z, az); aw = fmaf(v1, x1.w, aw);
    ax = fmaf(v2, x2.x, ax); ay = fmaf(v2, x2.y, ay);
    az = fmaf(v2, x2.z, az); aw = fmaf(v2, x2.w, aw);
    ax = fmaf(v3, x3.x, ax); ay = fmaf(v3, x3.y, ay);
    az = fmaf(v3, x3.z, az); aw = fmaf(v3, x3.w, aw);
  }
  for (; i < end; ++i) {
    int2 cv = CV[i];
    float v = __int_as_float(cv.y);
    float4 x = *(const float4*)(A + (size_t)cv.x * HID + c4);
    ax = fmaf(v, x.x, ax); ay = fmaf(v, x.y, ay);
    az = fmaf(v, x.z, az); aw = fmaf(v, x.w, aw);
  }

  // fused residual + JAX-exact dropout
  float4 res = *(const float4*)(A + (size_t)r * HID + c4);
  uint32_t e0 = (uint32_t)r * (uint32_t)HID + (uint32_t)c4;
  float4 o;
  o.x = keep_elem(k0, k1, e0 + 0u) ? (ax + res.x) / 0.9f : 0.0f;
  o.y = keep_elem(k0, k1, e0 + 1u) ? (ay + res.y) / 0.9f : 0.0f;
  o.z = keep_elem(k0, k1, e0 + 2u) ? (az + res.z) / 0.9f : 0.0f;
  o.w = keep_elem(k0, k1, e0 + 3u) ? (aw + res.w) / 0.9f : 0.0f;
  *(float4*)(B + (size_t)r * HID + c4) = o;
}

// ---- fallback (old) edge-parallel SpMM + separate dropres, used if ws too small ----
__global__ __launch_bounds__(256) void k_spmm(const int* __restrict__ rows,
                                              const int* __restrict__ cols,
                                              const float* __restrict__ vals,
                                              const float* __restrict__ A,
                                              float* __restrict__ B) {
  int e = blockIdx.x * 4 + (threadIdx.x >> 6);
  int lane = threadIdx.x & 63;
  if (e >= NNZ) return;
  int r = rows[e];
  int c = cols[e];
  float v = vals[e];
  float4 x = *(const float4*)(A + (size_t)c * HID + lane * 4);
  float* bp = B + (size_t)r * HID + lane * 4;
  unsafeAtomicAdd(bp + 0, v * x.x);
  unsafeAtomicAdd(bp + 1, v * x.y);
  unsafeAtomicAdd(bp + 2, v * x.z);
  unsafeAtomicAdd(bp + 3, v * x.w);
}

__global__ __launch_bounds__(256) void k_dropres(const float* __restrict__ A,
                                                 float* __restrict__ B,
                                                 uint32_t k0, uint32_t k1) {
  uint32_t e = blockIdx.x * 256 + threadIdx.x;
  if (e >= (uint32_t)N * HID) return;
  float m = B[e] + A[e];
  B[e] = keep_elem(k0, k1, e) ? (m / 0.9f) : 0.0f;
}

// h' = leaky(M @ W^T + b); M is [N,HID] f32, W is [NC,HID] f32 row-major.
// 64-row tile per block; m staged to LDS as [k][r] (broadcast b128 reads);
// W columns held in registers (4 contiguous output cols per thread).
template <int NC, bool WRITE_F32>
__global__ __launch_bounds__(256) void k_gemm(const float* __restrict__ M,
                                              const float* __restrict__ W,
                                              const float* __restrict__ bias,
                                              float* __restrict__ Aout,
                                              float* __restrict__ out,
                                              int colbase) {
  constexpr int CG = NC / 4;    // col groups (64 or 32)
  constexpr int RG = 256 / CG;  // row groups (4 or 8)
  constexpr int RPT = 64 / RG;  // rows per thread (16 or 8)
  __shared__ float m_s[64][68]; // [k][r]; pad keeps 16B alignment

  const int tid = threadIdx.x;
  const int j = tid % CG;       // this thread's col group -> cols 4j..4j+3
  const int rg = tid / CG;
  const int row0 = blockIdx.x * 64;
  const int r0 = rg * RPT;

  float acc[RPT][4];
#pragma unroll
  for (int i = 0; i < RPT; ++i)
#pragma unroll
    for (int c = 0; c < 4; ++c) acc[i][c] = 0.f;

  const int rr = tid >> 4;         // 0..15
  const int kk = (tid & 15) * 4;   // 0..60

#pragma unroll 1
  for (int kc = 0; kc < HID; kc += 64) {
    __syncthreads();
    // stage M[row0:row0+64, kc:kc+64] transposed into m_s[k][r]
#pragma unroll
    for (int p = 0; p < 4; ++p) {
      int r = p * 16 + rr;
      int grow = row0 + r;
      float4 v = make_float4(0.f, 0.f, 0.f, 0.f);
      if (grow < N) v = *(const float4*)(M + (size_t)grow * HID + kc + kk);
      m_s[kk + 0][r] = v.x;
      m_s[kk + 1][r] = v.y;
      m_s[kk + 2][r] = v.z;
      m_s[kk + 3][r] = v.w;
    }
    __syncthreads();

#pragma unroll 1
    for (int ks = 0; ks < 64; ks += 8) {
      float4 wa[4], wb[4];  // 8 f32 along k for each of 4 cols
#pragma unroll
      for (int c = 0; c < 4; ++c) {
        const float* wp = W + (size_t)(4 * j + c) * HID + kc + ks;
        wa[c] = *(const float4*)(wp);
        wb[c] = *(const float4*)(wp + 4);
      }
#pragma unroll
      for (int q = 0; q < 8; ++q) {
        float wf[4];
#pragma unroll
        for (int c = 0; c < 4; ++c) {
          const float* wv = (q < 4) ? (const float*)&wa[c] : (const float*)&wb[c];
          wf[c] = wv[q & 3];
        }
        const float* ms = &m_s[ks + q][r0];
#pragma unroll
        for (int ii = 0; ii < RPT / 4; ++ii) {
          float4 mv = *(const float4*)(ms + ii * 4);  // broadcast within row group
          const float mr[4] = {mv.x, mv.y, mv.z, mv.w};
#pragma unroll
          for (int t = 0; t < 4; ++t)
#pragma unroll
            for (int c = 0; c < 4; ++c)
              acc[ii * 4 + t][c] = fmaf(mr[t], wf[c], acc[ii * 4 + t][c]);
        }
      }
    }
  }

  float bv[4];
#pragma unroll
  for (int c = 0; c < 4; ++c) bv[c] = bias[4 * j + c];

#pragma unroll
  for (int i = 0; i < RPT; ++i) {
    int grow = row0 + r0 + i;
    if (grow < N) {
      float4 ov;
      float* ovp = (float*)&ov;
#pragma unroll
      for (int c = 0; c < 4; ++c) {
        float v = acc[i][c] + bv[c];
        ovp[c] = (v >= 0.f) ? v : NEG_SLOPE * v;
      }
      if (WRITE_F32)
        *(float4*)(Aout + (size_t)grow * HID + 4 * j) = ov;
      *(float4*)(out + (size_t)grow * OUTW + colbase + 4 * j) = ov;
    }
  }
}

// ---------------- host launcher ----------------
extern "C" void kernel_launch(void* const* d_in, const int* in_sizes, int n_in,
                              void* d_out, int out_size, void* d_ws, size_t ws_size,
                              hipStream_t stream) {
  (void)in_sizes; (void)n_in; (void)out_size;

  const int*   x_idx  = (const int*)d_in[0];
  const float* emb    = (const float*)d_in[1];
  const int*   g_rows = (const int*)d_in[2];
  const int*   g_cols = (const int*)d_in[3];
  const float* g_vals = (const float*)d_in[4];
  const float* W1 = (const float*)d_in[5];
  const float* b1 = (const float*)d_in[6];
  const float* W2 = (const float*)d_in[7];
  const float* b2 = (const float*)d_in[8];
  const float* W3 = (const float*)d_in[9];
  const float* b3 = (const float*)d_in[10];
  float* out = (float*)d_out;

  // ---- workspace layout ----
  float* A = (float*)d_ws;                 // current layer input h  [N,HID] f32
  float* B = A + (size_t)N * HID;          // spmm/m buffer          [N,HID] f32
  int*   RO = (int*)(B + (size_t)N * HID); // row offsets [N+1] (+1 pad for 8B align)
  int*   C  = RO + (N + 2);                // scatter cursors [N]
  int2*  CV = (int2*)(C + N);              // packed (col,val) [NNZ], 8B aligned
  const size_t NEED = (size_t)(B + (size_t)N * HID - A) * sizeof(float)
                    + (size_t)(N + 2 + N) * sizeof(int)
                    + (size_t)NNZ * sizeof(int2);
  const bool use_csr = (ws_size >= NEED);

  // dropout keys: dk = split(key(42), 3), reproduced host-side
  uint32_t dk[3][2];
#if THREEFRY_PARTITIONABLE
  for (uint32_t i = 0; i < 3; ++i)
    threefry2x32(0u, 42u, 0u, i, dk[i][0], dk[i][1]);
#else
  {
    uint32_t a0, c0, a1, c1, a2, c2;
    threefry2x32(0u, 42u, 0u, 3u, a0, c0);
    threefry2x32(0u, 42u, 1u, 4u, a1, c1);
    threefry2x32(0u, 42u, 2u, 5u, a2, c2);
    dk[0][0] = a0; dk[0][1] = a1;
    dk[1][0] = a2; dk[1][1] = c0;
    dk[2][0] = c1; dk[2][1] = c2;
  }
#endif

  const int gemm_blocks = (N + 63) / 64;   // 1563

  k_gather<<<(N * 64) / 256, 256, 0, stream>>>(x_idx, emb, A, out);

  if (use_csr) {
    // build CSR once; the graph is reused by all 3 SpMMs
    k_zero_i<<<(N + 2 + 255) / 256, 256, 0, stream>>>(RO, N + 2);
    k_hist<<<(NNZ + 255) / 256, 256, 0, stream>>>(g_rows, RO);
    k_scan<<<1, 256, 0, stream>>>(RO, C);
    k_scatter<<<(NNZ + 255) / 256, 256, 0, stream>>>(g_rows, g_cols, g_vals, C, CV);
  }

  const float* Ws[3] = {W1, W2, W3};
  const float* bs[3] = {b1, b2, b3};
  for (int l = 0; l < 3; ++l) {
    if (use_csr) {
      // row-parallel SpMM with fused residual + dropout; no zeroing, no atomics
      k_spmm_csr<<<(N + 3) / 4, 256, 0, stream>>>(RO, CV, A, B, dk[l][0], dk[l][1]);
    } else {
      k_zero<<<(N * HID / 4 + 255) / 256, 256, 0, stream>>>((float4*)B, N * HID / 4);
      k_spmm<<<NNZ / 4, 256, 0, stream>>>(g_rows, g_cols, g_vals, A, B);
      k_dropres<<<(N * HID) / 256, 256, 0, stream>>>(A, B, dk[l][0], dk[l][1]);
    }
    if (l < 2)
      k_gemm<HID, true><<<gemm_blocks, 256, 0, stream>>>(B, Ws[l], bs[l], A, out, HID * (l + 1));
    else
      k_gemm<IEMB, false><<<gemm_blocks, 256, 0, stream>>>(B, Ws[2], bs[2], nullptr, out, 3 * HID);
  }
}

// Round 3
// 2784.786 us; speedup vs baseline: 11.9299x; 1.1816x over previous
//
#include <hip/hip_runtime.h>
#include <stdint.h>
#include <stddef.h>

// ---------------- problem constants ----------------
static constexpr int N    = 100000;
static constexpr int HID  = 256;
static constexpr int IEMB = 128;
static constexpr int NNZ  = 3200000;
static constexpr int OUTW = 3 * HID + IEMB;  // 896
static constexpr float NEG_SLOPE = 0.2f;

// JAX threefry variant: 1 = partitionable (default in JAX >= 0.5.0), 0 = original
#define THREEFRY_PARTITIONABLE 1

typedef __attribute__((ext_vector_type(8))) short bf16x8;
typedef __attribute__((ext_vector_type(4))) float f32x4;
typedef __attribute__((ext_vector_type(4))) unsigned short us4;

// ---------------- threefry2x32 (JAX-compatible) ----------------
__host__ __device__ inline uint32_t rotl32(uint32_t v, int r) {
  return (v << r) | (v >> (32 - r));
}

__host__ __device__ inline void threefry2x32(uint32_t k0, uint32_t k1,
                                             uint32_t x0, uint32_t x1,
                                             uint32_t& o0, uint32_t& o1) {
  const uint32_t k2 = k0 ^ k1 ^ 0x1BD11BDAu;
  x0 += k0; x1 += k1;
  // rounds 1-4
  x0 += x1; x1 = rotl32(x1, 13); x1 ^= x0;
  x0 += x1; x1 = rotl32(x1, 15); x1 ^= x0;
  x0 += x1; x1 = rotl32(x1, 26); x1 ^= x0;
  x0 += x1; x1 = rotl32(x1,  6); x1 ^= x0;
  x0 += k1; x1 += k2 + 1u;
  // rounds 5-8
  x0 += x1; x1 = rotl32(x1, 17); x1 ^= x0;
  x0 += x1; x1 = rotl32(x1, 29); x1 ^= x0;
  x0 += x1; x1 = rotl32(x1, 16); x1 ^= x0;
  x0 += x1; x1 = rotl32(x1, 24); x1 ^= x0;
  x0 += k2; x1 += k0 + 2u;
  // rounds 9-12
  x0 += x1; x1 = rotl32(x1, 13); x1 ^= x0;
  x0 += x1; x1 = rotl32(x1, 15); x1 ^= x0;
  x0 += x1; x1 = rotl32(x1, 26); x1 ^= x0;
  x0 += x1; x1 = rotl32(x1,  6); x1 ^= x0;
  x0 += k0; x1 += k1 + 3u;
  // rounds 13-16
  x0 += x1; x1 = rotl32(x1, 17); x1 ^= x0;
  x0 += x1; x1 = rotl32(x1, 29); x1 ^= x0;
  x0 += x1; x1 = rotl32(x1, 16); x1 ^= x0;
  x0 += x1; x1 = rotl32(x1, 24); x1 ^= x0;
  x0 += k1; x1 += k2 + 4u;
  // rounds 17-20
  x0 += x1; x1 = rotl32(x1, 13); x1 ^= x0;
  x0 += x1; x1 = rotl32(x1, 15); x1 ^= x0;
  x0 += x1; x1 = rotl32(x1, 26); x1 ^= x0;
  x0 += x1; x1 = rotl32(x1,  6); x1 ^= x0;
  x0 += k2; x1 += k0 + 5u;
  o0 = x0; o1 = x1;
}

// keep-mask for flat element index e of a [N,HID] dropout draw under key (k0,k1)
__device__ inline bool keep_elem(uint32_t k0, uint32_t k1, uint32_t e) {
  uint32_t o0, o1, bits;
#if THREEFRY_PARTITIONABLE
  threefry2x32(k0, k1, 0u, e, o0, o1);   // counter = 64-bit flat index (hi=0, lo=e)
  bits = o0 ^ o1;                        // 32-bit draw folds the two output words
#else
  const uint32_t H = (uint32_t)(N) * (uint32_t)(HID) / 2u;  // 12,800,000
  if (e < H) { threefry2x32(k0, k1, e, e + H, o0, o1); bits = o0; }
  else       { threefry2x32(k0, k1, e - H, e, o0, o1); bits = o1; }
#endif
  float u = __uint_as_float((bits >> 9) | 0x3f800000u) - 1.0f;  // [0,1)
  return u < 0.9f;  // bernoulli(keep=0.9): uniform < p
}

// ---------------- bf16 split helpers ----------------
__device__ inline unsigned short f2bf_rne(float x) {
  uint32_t u = __float_as_uint(x);
  uint32_t r = (u + 0x7FFFu + ((u >> 16) & 1u)) >> 16;
  return (unsigned short)r;
}
__device__ inline float bf2f(unsigned short h) {
  return __uint_as_float(((uint32_t)h) << 16);
}

// ---------------- kernels (all float32) ----------------

// x = embed[x_idx]; write f32 copy to A (stride HID) and to out cols [0,256)
__global__ __launch_bounds__(256) void k_gather(const int* __restrict__ xidx,
                                                const float* __restrict__ emb,
                                                float* __restrict__ A,
                                                float* __restrict__ out) {
  int t = blockIdx.x * 256 + threadIdx.x;          // over N*64 chunks of 4 elems
  int n = t >> 6;
  int c4 = (t & 63) * 4;
  if (n >= N) return;
  int src = xidx[n];
  float4 v = *(const float4*)(emb + (size_t)src * HID + c4);
  *(float4*)(out + (size_t)n * OUTW + c4) = v;
  *(float4*)(A + (size_t)n * HID + c4) = v;
}

__global__ __launch_bounds__(256) void k_zero(float4* __restrict__ p, int n4) {
  int i = blockIdx.x * 256 + threadIdx.x;
  if (i < n4) p[i] = make_float4(0.f, 0.f, 0.f, 0.f);
}

__global__ __launch_bounds__(256) void k_zero_i(int* __restrict__ p, int n) {
  int i = blockIdx.x * 256 + threadIdx.x;
  if (i < n) p[i] = 0;
}

// split W into bf16 hi/lo halves (Markidis decomposition)
__global__ __launch_bounds__(256) void k_wsplit(const float* __restrict__ W,
                                                unsigned short* __restrict__ whi,
                                                unsigned short* __restrict__ wlo,
                                                int n) {
  int i = blockIdx.x * 256 + threadIdx.x;
  if (i >= n) return;
  float w = W[i];
  unsigned short h = f2bf_rne(w);
  unsigned short l = f2bf_rne(w - bf2f(h));
  whi[i] = h; wlo[i] = l;
}

// ---- CSR build: histogram -> single-block scan -> scatter (col,val) pairs ----

__global__ __launch_bounds__(256) void k_hist(const int* __restrict__ rows,
                                              int* __restrict__ RO) {
  int e = blockIdx.x * 256 + threadIdx.x;
  if (e < NNZ) atomicAdd(&RO[rows[e]], 1);
}

// RO[0..N-1] holds counts on entry. On exit: RO[0..N] = exclusive scan (RO[N]=NNZ),
// C[r] = RO[r] (scatter cursors). Single block of 256 threads.
__global__ __launch_bounds__(256) void k_scan(int* __restrict__ RO, int* __restrict__ C) {
  __shared__ int part[256];
  const int T = 256;
  const int K = (N + T - 1) / T;  // 391
  int t = threadIdx.x;
  int lo = t * K;
  int hi = lo + K; if (hi > N) hi = N;
  int s = 0;
  for (int i = lo; i < hi; ++i) s += RO[i];
  part[t] = s;
  __syncthreads();
  if (t == 0) {
    int run = 0;
    for (int i = 0; i < T; ++i) { int v = part[i]; part[i] = run; run += v; }
  }
  __syncthreads();
  int run = part[t];
  for (int i = lo; i < hi; ++i) {
    int v = RO[i];
    RO[i] = run;
    C[i]  = run;
    run += v;
  }
  if (t == T - 1) RO[N] = run;  // == NNZ
}

__global__ __launch_bounds__(256) void k_scatter(const int* __restrict__ rows,
                                                 const int* __restrict__ cols,
                                                 const float* __restrict__ vals,
                                                 int* __restrict__ C,
                                                 int2* __restrict__ CV) {
  int e = blockIdx.x * 256 + threadIdx.x;
  if (e >= NNZ) return;
  int r = rows[e];
  int pos = atomicAdd(&C[r], 1);
  CV[pos] = make_int2(cols[e], __float_as_int(vals[e]));
}

// Row-parallel CSR SpMM, fused residual + dropout:
// B[r] = dropout(sum_e v_e * A[col_e] + A[r]).
// One wave per row: 64 lanes x float4 = full 256-wide row in registers. No atomics.
__global__ __launch_bounds__(256) void k_spmm_csr(const int* __restrict__ RO,
                                                  const int2* __restrict__ CV,
                                                  const float* __restrict__ A,
                                                  float* __restrict__ B,
                                                  uint32_t k0, uint32_t k1) {
  int r = blockIdx.x * 4 + (threadIdx.x >> 6);
  if (r >= N) return;
  int c4 = (threadIdx.x & 63) * 4;
  int beg = RO[r], end = RO[r + 1];

  float ax = 0.f, ay = 0.f, az = 0.f, aw = 0.f;
  int i = beg;
  // 4-way unrolled edge loop: 4 independent gathers in flight per iteration
  for (; i + 3 < end; i += 4) {
    int2 cv0 = CV[i + 0], cv1 = CV[i + 1], cv2 = CV[i + 2], cv3 = CV[i + 3];
    float4 x0 = *(const float4*)(A + (size_t)cv0.x * HID + c4);
    float4 x1 = *(const float4*)(A + (size_t)cv1.x * HID + c4);
    float4 x2 = *(const float4*)(A + (size_t)cv2.x * HID + c4);
    float4 x3 = *(const float4*)(A + (size_t)cv3.x * HID + c4);
    float v0 = __int_as_float(cv0.y), v1 = __int_as_float(cv1.y);
    float v2 = __int_as_float(cv2.y), v3 = __int_as_float(cv3.y);
    ax = fmaf(v0, x0.x, ax); ay = fmaf(v0, x0.y, ay);
    az = fmaf(v0, x0.z, az); aw = fmaf(v0, x0.w, aw);
    ax = fmaf(v1, x1.x, ax); ay = fmaf(v1, x1.y, ay);
    az = fmaf(v1, x1.z, az); aw = fmaf(v1, x1.w, aw);
    ax = fmaf(v2, x2.x, ax); ay = fmaf(v2, x2.y, ay);
    az = fmaf(v2, x2.z, az); aw = fmaf(v2, x2.w, aw);
    ax = fmaf(v3, x3.x, ax); ay = fmaf(v3, x3.y, ay);
    az = fmaf(v3, x3.z, az); aw = fmaf(v3, x3.w, aw);
  }
  for (; i < end; ++i) {
    int2 cv = CV[i];
    float v = __int_as_float(cv.y);
    float4 x = *(const float4*)(A + (size_t)cv.x * HID + c4);
    ax = fmaf(v, x.x, ax); ay = fmaf(v, x.y, ay);
    az = fmaf(v, x.z, az); aw = fmaf(v, x.w, aw);
  }

  // fused residual + JAX-exact dropout
  float4 res = *(const float4*)(A + (size_t)r * HID + c4);
  uint32_t e0 = (uint32_t)r * (uint32_t)HID + (uint32_t)c4;
  float4 o;
  o.x = keep_elem(k0, k1, e0 + 0u) ? (ax + res.x) / 0.9f : 0.0f;
  o.y = keep_elem(k0, k1, e0 + 1u) ? (ay + res.y) / 0.9f : 0.0f;
  o.z = keep_elem(k0, k1, e0 + 2u) ? (az + res.z) / 0.9f : 0.0f;
  o.w = keep_elem(k0, k1, e0 + 3u) ? (aw + res.w) / 0.9f : 0.0f;
  *(float4*)(B + (size_t)r * HID + c4) = o;
}

// ---- MFMA GEMM: out = leaky(M @ W^T + b) via split-bf16 (hi*hi + hi*lo + lo*hi) ----
// Block: 256 threads = 4 waves; 64-row tile; wave w covers cols [w*NC/4, (w+1)*NC/4).
// M staged to LDS as split bf16 in K-chunks of 128, XOR-swizzled against bank conflicts.
template <int NC, bool WRITE_F32>
__global__ __launch_bounds__(256) void k_gemm_mfma(const float* __restrict__ M,
                                                   const unsigned short* __restrict__ Whi,
                                                   const unsigned short* __restrict__ Wlo,
                                                   const float* __restrict__ bias,
                                                   float* __restrict__ Aout,
                                                   float* __restrict__ out,
                                                   int colbase) {
  constexpr int WC = NC / 4;   // cols per wave (64 or 32)
  constexpr int CT = WC / 16;  // 16x16 col tiles per wave (4 or 2)
  __shared__ __align__(16) unsigned short mhi[64 * 128];
  __shared__ __align__(16) unsigned short mlo[64 * 128];

  const int tid  = threadIdx.x;
  const int wave = tid >> 6;
  const int lane = tid & 63;
  const int l15  = lane & 15;
  const int lhi  = lane >> 4;      // 0..3
  const int row0 = blockIdx.x * 64;
  const int wc0  = wave * WC;

  const f32x4 fzero = {0.f, 0.f, 0.f, 0.f};
  f32x4 acc[4][CT];
#pragma unroll
  for (int rt = 0; rt < 4; ++rt)
#pragma unroll
    for (int ct = 0; ct < CT; ++ct) acc[rt][ct] = fzero;

  const int tk = (tid & 31) * 4;   // staging k offset within chunk (0..124)
  const int tr = tid >> 5;         // staging row group 0..7

#pragma unroll 1
  for (int kc = 0; kc < HID; kc += 128) {
    __syncthreads();
    // stage M[row0:row0+64, kc:kc+128] -> split bf16, swizzled: elem k ^= (row&7)<<3
#pragma unroll
    for (int p = 0; p < 8; ++p) {
      int r = p * 8 + tr;
      int grow = row0 + r;
      float4 v = make_float4(0.f, 0.f, 0.f, 0.f);
      if (grow < N) v = *(const float4*)(M + (size_t)grow * HID + kc + tk);
      float vv[4] = {v.x, v.y, v.z, v.w};
      us4 h, l;
#pragma unroll
      for (int c = 0; c < 4; ++c) {
        unsigned short hh = f2bf_rne(vv[c]);
        h[c] = hh;
        l[c] = f2bf_rne(vv[c] - bf2f(hh));
      }
      int sidx = r * 128 + (tk ^ ((r & 7) << 3));
      *(us4*)(&mhi[sidx]) = h;
      *(us4*)(&mlo[sidx]) = l;
    }
    __syncthreads();

#pragma unroll
    for (int ks = 0; ks < 128; ks += 32) {
      const int kf = ks + lhi * 8;  // this lane's k offset within chunk
      // A fragments (hi/lo) for 4 row tiles from LDS
      bf16x8 ah[4], al[4];
#pragma unroll
      for (int rt = 0; rt < 4; ++rt) {
        int r = rt * 16 + l15;
        int idx = r * 128 + (kf ^ ((r & 7) << 3));
        ah[rt] = *(const bf16x8*)(&mhi[idx]);
        al[rt] = *(const bf16x8*)(&mlo[idx]);
      }
      // B fragments from global (L2-resident W) + MFMA
#pragma unroll
      for (int ct = 0; ct < CT; ++ct) {
        int col = wc0 + ct * 16 + l15;
        const unsigned short* wph = Whi + (size_t)col * HID + kc + kf;
        const unsigned short* wpl = Wlo + (size_t)col * HID + kc + kf;
        bf16x8 bh = *(const bf16x8*)wph;
        bf16x8 bl = *(const bf16x8*)wpl;
#pragma unroll
        for (int rt = 0; rt < 4; ++rt) {
          acc[rt][ct] = __builtin_amdgcn_mfma_f32_16x16x32_bf16(ah[rt], bh, acc[rt][ct], 0, 0, 0);
          acc[rt][ct] = __builtin_amdgcn_mfma_f32_16x16x32_bf16(ah[rt], bl, acc[rt][ct], 0, 0, 0);
          acc[rt][ct] = __builtin_amdgcn_mfma_f32_16x16x32_bf16(al[rt], bh, acc[rt][ct], 0, 0, 0);
        }
      }
    }
  }

  // epilogue: bias + leaky + store. C/D layout: col = lane&15, row = (lane>>4)*4 + reg.
#pragma unroll
  for (int ct = 0; ct < CT; ++ct) {
    int col = wc0 + ct * 16 + l15;
    float bv = bias[col];
#pragma unroll
    for (int rt = 0; rt < 4; ++rt) {
#pragma unroll
      for (int rg = 0; rg < 4; ++rg) {
        int grow = row0 + rt * 16 + lhi * 4 + rg;
        if (grow < N) {
          float v = acc[rt][ct][rg] + bv;
          v = (v >= 0.f) ? v : NEG_SLOPE * v;
          out[(size_t)grow * OUTW + colbase + col] = v;
          if (WRITE_F32) Aout[(size_t)grow * HID + col] = v;
        }
      }
    }
  }
}

// ---- fallback (old) path kernels, used if workspace too small ----
__global__ __launch_bounds__(256) void k_spmm(const int* __restrict__ rows,
                                              const int* __restrict__ cols,
                                              const float* __restrict__ vals,
                                              const float* __restrict__ A,
                                              float* __restrict__ B) {
  int e = blockIdx.x * 4 + (threadIdx.x >> 6);
  int lane = threadIdx.x & 63;
  if (e >= NNZ) return;
  int r = rows[e];
  int c = cols[e];
  float v = vals[e];
  float4 x = *(const float4*)(A + (size_t)c * HID + lane * 4);
  float* bp = B + (size_t)r * HID + lane * 4;
  unsafeAtomicAdd(bp + 0, v * x.x);
  unsafeAtomicAdd(bp + 1, v * x.y);
  unsafeAtomicAdd(bp + 2, v * x.z);
  unsafeAtomicAdd(bp + 3, v * x.w);
}

__global__ __launch_bounds__(256) void k_dropres(const float* __restrict__ A,
                                                 float* __restrict__ B,
                                                 uint32_t k0, uint32_t k1) {
  uint32_t e = blockIdx.x * 256 + threadIdx.x;
  if (e >= (uint32_t)N * HID) return;
  float m = B[e] + A[e];
  B[e] = keep_elem(k0, k1, e) ? (m / 0.9f) : 0.0f;
}

// old VALU GEMM (fallback only)
template <int NC, bool WRITE_F32>
__global__ __launch_bounds__(256) void k_gemm(const float* __restrict__ M,
                                              const float* __restrict__ W,
                                              const float* __restrict__ bias,
                                              float* __restrict__ Aout,
                                              float* __restrict__ out,
                                              int colbase) {
  constexpr int CG = NC / 4;    // col groups (64 or 32)
  constexpr int RG = 256 / CG;  // row groups (4 or 8)
  constexpr int RPT = 64 / RG;  // rows per thread (16 or 8)
  __shared__ float m_s[64][68];

  const int tid = threadIdx.x;
  const int j = tid % CG;
  const int rg = tid / CG;
  const int row0 = blockIdx.x * 64;
  const int r0 = rg * RPT;

  float acc[RPT][4];
#pragma unroll
  for (int i = 0; i < RPT; ++i)
#pragma unroll
    for (int c = 0; c < 4; ++c) acc[i][c] = 0.f;

  const int rr = tid >> 4;
  const int kk = (tid & 15) * 4;

#pragma unroll 1
  for (int kc = 0; kc < HID; kc += 64) {
    __syncthreads();
#pragma unroll
    for (int p = 0; p < 4; ++p) {
      int r = p * 16 + rr;
      int grow = row0 + r;
      float4 v = make_float4(0.f, 0.f, 0.f, 0.f);
      if (grow < N) v = *(const float4*)(M + (size_t)grow * HID + kc + kk);
      m_s[kk + 0][r] = v.x;
      m_s[kk + 1][r] = v.y;
      m_s[kk + 2][r] = v.z;
      m_s[kk + 3][r] = v.w;
    }
    __syncthreads();

#pragma unroll 1
    for (int ks = 0; ks < 64; ks += 8) {
      float4 wa[4], wb[4];
#pragma unroll
      for (int c = 0; c < 4; ++c) {
        const float* wp = W + (size_t)(4 * j + c) * HID + kc + ks;
        wa[c] = *(const float4*)(wp);
        wb[c] = *(const float4*)(wp + 4);
      }
#pragma unroll
      for (int q = 0; q < 8; ++q) {
        float wf[4];
#pragma unroll
        for (int c = 0; c < 4; ++c) {
          const float* wv = (q < 4) ? (const float*)&wa[c] : (const float*)&wb[c];
          wf[c] = wv[q & 3];
        }
        const float* ms = &m_s[ks + q][r0];
#pragma unroll
        for (int ii = 0; ii < RPT / 4; ++ii) {
          float4 mv = *(const float4*)(ms + ii * 4);
          const float mr[4] = {mv.x, mv.y, mv.z, mv.w};
#pragma unroll
          for (int t = 0; t < 4; ++t)
#pragma unroll
            for (int c = 0; c < 4; ++c)
              acc[ii * 4 + t][c] = fmaf(mr[t], wf[c], acc[ii * 4 + t][c]);
        }
      }
    }
  }

  float bv[4];
#pragma unroll
  for (int c = 0; c < 4; ++c) bv[c] = bias[4 * j + c];

#pragma unroll
  for (int i = 0; i < RPT; ++i) {
    int grow = row0 + r0 + i;
    if (grow < N) {
      float4 ov;
      float* ovp = (float*)&ov;
#pragma unroll
      for (int c = 0; c < 4; ++c) {
        float v = acc[i][c] + bv[c];
        ovp[c] = (v >= 0.f) ? v : NEG_SLOPE * v;
      }
      if (WRITE_F32)
        *(float4*)(Aout + (size_t)grow * HID + 4 * j) = ov;
      *(float4*)(out + (size_t)grow * OUTW + colbase + 4 * j) = ov;
    }
  }
}

// ---------------- host launcher ----------------
extern "C" void kernel_launch(void* const* d_in, const int* in_sizes, int n_in,
                              void* d_out, int out_size, void* d_ws, size_t ws_size,
                              hipStream_t stream) {
  (void)in_sizes; (void)n_in; (void)out_size;

  const int*   x_idx  = (const int*)d_in[0];
  const float* emb    = (const float*)d_in[1];
  const int*   g_rows = (const int*)d_in[2];
  const int*   g_cols = (const int*)d_in[3];
  const float* g_vals = (const float*)d_in[4];
  const float* W1 = (const float*)d_in[5];
  const float* b1 = (const float*)d_in[6];
  const float* W2 = (const float*)d_in[7];
  const float* b2 = (const float*)d_in[8];
  const float* W3 = (const float*)d_in[9];
  const float* b3 = (const float*)d_in[10];
  float* out = (float*)d_out;

  // ---- workspace layout ----
  float* A = (float*)d_ws;                 // current layer input h  [N,HID] f32
  float* B = A + (size_t)N * HID;          // spmm/m buffer          [N,HID] f32
  int*   RO = (int*)(B + (size_t)N * HID); // row offsets [N+1] (+pad)
  int*   C  = RO + (N + 2);                // scatter cursors [N]
  int2*  CV = (int2*)(C + N);              // packed (col,val) [NNZ], 8B aligned
  uintptr_t wsp = ((uintptr_t)(CV + NNZ) + 63) & ~(uintptr_t)63;
  unsigned short* Wh0 = (unsigned short*)wsp;      // split-bf16 weights
  unsigned short* Wl0 = Wh0 + 65536;
  unsigned short* Wh1 = Wl0 + 65536;
  unsigned short* Wl1 = Wh1 + 65536;
  unsigned short* Wh2 = Wl1 + 65536;               // W3 is [128,256]
  unsigned short* Wl2 = Wh2 + 32768;
  const size_t NEED = (size_t)N * HID * 2 * sizeof(float)
                    + (size_t)(N + 2 + N) * sizeof(int)
                    + (size_t)NNZ * sizeof(int2)
                    + 64
                    + (size_t)(4 * 65536 + 2 * 32768) * sizeof(unsigned short);
  const bool use_csr = (ws_size >= NEED);

  // dropout keys: dk = split(key(42), 3), reproduced host-side
  uint32_t dk[3][2];
#if THREEFRY_PARTITIONABLE
  for (uint32_t i = 0; i < 3; ++i)
    threefry2x32(0u, 42u, 0u, i, dk[i][0], dk[i][1]);
#else
  {
    uint32_t a0, c0, a1, c1, a2, c2;
    threefry2x32(0u, 42u, 0u, 3u, a0, c0);
    threefry2x32(0u, 42u, 1u, 4u, a1, c1);
    threefry2x32(0u, 42u, 2u, 5u, a2, c2);
    dk[0][0] = a0; dk[0][1] = a1;
    dk[1][0] = a2; dk[1][1] = c0;
    dk[2][0] = c1; dk[2][1] = c2;
  }
#endif

  const int gemm_blocks = (N + 63) / 64;   // 1563

  k_gather<<<(N * 64) / 256, 256, 0, stream>>>(x_idx, emb, A, out);

  const float* Ws[3] = {W1, W2, W3};
  const float* bs[3] = {b1, b2, b3};
  unsigned short* Whs[3] = {Wh0, Wh1, Wh2};
  unsigned short* Wls[3] = {Wl0, Wl1, Wl2};

  if (use_csr) {
    // build CSR once; the graph is reused by all 3 SpMMs
    k_zero_i<<<(N + 2 + 255) / 256, 256, 0, stream>>>(RO, N + 2);
    k_hist<<<(NNZ + 255) / 256, 256, 0, stream>>>(g_rows, RO);
    k_scan<<<1, 256, 0, stream>>>(RO, C);
    k_scatter<<<(NNZ + 255) / 256, 256, 0, stream>>>(g_rows, g_cols, g_vals, C, CV);
    // split weights to bf16 hi/lo once
    k_wsplit<<<(65536 + 255) / 256, 256, 0, stream>>>(W1, Wh0, Wl0, 65536);
    k_wsplit<<<(65536 + 255) / 256, 256, 0, stream>>>(W2, Wh1, Wl1, 65536);
    k_wsplit<<<(32768 + 255) / 256, 256, 0, stream>>>(W3, Wh2, Wl2, 32768);
  }

  for (int l = 0; l < 3; ++l) {
    if (use_csr) {
      k_spmm_csr<<<(N + 3) / 4, 256, 0, stream>>>(RO, CV, A, B, dk[l][0], dk[l][1]);
      if (l < 2)
        k_gemm_mfma<HID, true><<<gemm_blocks, 256, 0, stream>>>(B, Whs[l], Wls[l], bs[l], A, out, HID * (l + 1));
      else
        k_gemm_mfma<IEMB, false><<<gemm_blocks, 256, 0, stream>>>(B, Whs[2], Wls[2], bs[2], nullptr, out, 3 * HID);
    } else {
      k_zero<<<(N * HID / 4 + 255) / 256, 256, 0, stream>>>((float4*)B, N * HID / 4);
      k_spmm<<<NNZ / 4, 256, 0, stream>>>(g_rows, g_cols, g_vals, A, B);
      k_dropres<<<(N * HID) / 256, 256, 0, stream>>>(A, B, dk[l][0], dk[l][1]);
      if (l < 2)
        k_gemm<HID, true><<<gemm_blocks, 256, 0, stream>>>(B, Ws[l], bs[l], A, out, HID * (l + 1));
      else
        k_gemm<IEMB, false><<<gemm_blocks, 256, 0, stream>>>(B, Ws[2], bs[2], nullptr, out, 3 * HID);
    }
  }
}

// Round 4
// 2277.425 us; speedup vs baseline: 14.5876x; 1.2228x over previous
//
#include <hip/hip_runtime.h>
#include <stdint.h>
#include <stddef.h>

// ---------------- problem constants ----------------
static constexpr int N    = 100000;
static constexpr int HID  = 256;
static constexpr int IEMB = 128;
static constexpr int NNZ  = 3200000;
static constexpr int OUTW = 3 * HID + IEMB;  // 896
static constexpr float NEG_SLOPE = 0.2f;

// JAX threefry variant: 1 = partitionable (default in JAX >= 0.5.0), 0 = original
#define THREEFRY_PARTITIONABLE 1

typedef __attribute__((ext_vector_type(8))) short bf16x8;
typedef __attribute__((ext_vector_type(4))) float f32x4;
typedef __attribute__((ext_vector_type(4))) unsigned short us4;

// ---------------- threefry2x32 (JAX-compatible) ----------------
__host__ __device__ inline uint32_t rotl32(uint32_t v, int r) {
  return (v << r) | (v >> (32 - r));
}

__host__ __device__ inline void threefry2x32(uint32_t k0, uint32_t k1,
                                             uint32_t x0, uint32_t x1,
                                             uint32_t& o0, uint32_t& o1) {
  const uint32_t k2 = k0 ^ k1 ^ 0x1BD11BDAu;
  x0 += k0; x1 += k1;
  // rounds 1-4
  x0 += x1; x1 = rotl32(x1, 13); x1 ^= x0;
  x0 += x1; x1 = rotl32(x1, 15); x1 ^= x0;
  x0 += x1; x1 = rotl32(x1, 26); x1 ^= x0;
  x0 += x1; x1 = rotl32(x1,  6); x1 ^= x0;
  x0 += k1; x1 += k2 + 1u;
  // rounds 5-8
  x0 += x1; x1 = rotl32(x1, 17); x1 ^= x0;
  x0 += x1; x1 = rotl32(x1, 29); x1 ^= x0;
  x0 += x1; x1 = rotl32(x1, 16); x1 ^= x0;
  x0 += x1; x1 = rotl32(x1, 24); x1 ^= x0;
  x0 += k2; x1 += k0 + 2u;
  // rounds 9-12
  x0 += x1; x1 = rotl32(x1, 13); x1 ^= x0;
  x0 += x1; x1 = rotl32(x1, 15); x1 ^= x0;
  x0 += x1; x1 = rotl32(x1, 26); x1 ^= x0;
  x0 += x1; x1 = rotl32(x1,  6); x1 ^= x0;
  x0 += k0; x1 += k1 + 3u;
  // rounds 13-16
  x0 += x1; x1 = rotl32(x1, 17); x1 ^= x0;
  x0 += x1; x1 = rotl32(x1, 29); x1 ^= x0;
  x0 += x1; x1 = rotl32(x1, 16); x1 ^= x0;
  x0 += x1; x1 = rotl32(x1, 24); x1 ^= x0;
  x0 += k1; x1 += k2 + 4u;
  // rounds 17-20
  x0 += x1; x1 = rotl32(x1, 13); x1 ^= x0;
  x0 += x1; x1 = rotl32(x1, 15); x1 ^= x0;
  x0 += x1; x1 = rotl32(x1, 26); x1 ^= x0;
  x0 += x1; x1 = rotl32(x1,  6); x1 ^= x0;
  x0 += k2; x1 += k0 + 5u;
  o0 = x0; o1 = x1;
}

// keep-mask for flat element index e of a [N,HID] dropout draw under key (k0,k1)
__device__ inline bool keep_elem(uint32_t k0, uint32_t k1, uint32_t e) {
  uint32_t o0, o1, bits;
#if THREEFRY_PARTITIONABLE
  threefry2x32(k0, k1, 0u, e, o0, o1);   // counter = 64-bit flat index (hi=0, lo=e)
  bits = o0 ^ o1;                        // 32-bit draw folds the two output words
#else
  const uint32_t H = (uint32_t)(N) * (uint32_t)(HID) / 2u;  // 12,800,000
  if (e < H) { threefry2x32(k0, k1, e, e + H, o0, o1); bits = o0; }
  else       { threefry2x32(k0, k1, e - H, e, o0, o1); bits = o1; }
#endif
  float u = __uint_as_float((bits >> 9) | 0x3f800000u) - 1.0f;  // [0,1)
  return u < 0.9f;  // bernoulli(keep=0.9): uniform < p
}

// ---------------- bf16 helpers ----------------
__device__ inline unsigned short f2bf_rne(float x) {
  uint32_t u = __float_as_uint(x);
  uint32_t r = (u + 0x7FFFu + ((u >> 16) & 1u)) >> 16;
  return (unsigned short)r;
}
__device__ inline float bf2f(unsigned short h) {
  return __uint_as_float(((uint32_t)h) << 16);
}

// ---------------- kernels (all float32) ----------------

// x = embed[x_idx]; write f32 copy to A (stride HID), bf16 copy to Abf, and out cols [0,256)
__global__ __launch_bounds__(256) void k_gather(const int* __restrict__ xidx,
                                                const float* __restrict__ emb,
                                                float* __restrict__ A,
                                                unsigned short* __restrict__ Abf,
                                                float* __restrict__ out) {
  int t = blockIdx.x * 256 + threadIdx.x;          // over N*64 chunks of 4 elems
  int n = t >> 6;
  int c4 = (t & 63) * 4;
  if (n >= N) return;
  int src = xidx[n];
  float4 v = *(const float4*)(emb + (size_t)src * HID + c4);
  *(float4*)(out + (size_t)n * OUTW + c4) = v;
  *(float4*)(A + (size_t)n * HID + c4) = v;
  if (Abf) {
    us4 q;
    q[0] = f2bf_rne(v.x); q[1] = f2bf_rne(v.y);
    q[2] = f2bf_rne(v.z); q[3] = f2bf_rne(v.w);
    *(us4*)(Abf + (size_t)n * HID + c4) = q;
  }
}

__global__ __launch_bounds__(256) void k_zero(float4* __restrict__ p, int n4) {
  int i = blockIdx.x * 256 + threadIdx.x;
  if (i < n4) p[i] = make_float4(0.f, 0.f, 0.f, 0.f);
}

__global__ __launch_bounds__(256) void k_zero_i(int* __restrict__ p, int n) {
  int i = blockIdx.x * 256 + threadIdx.x;
  if (i < n) p[i] = 0;
}

// split W into bf16 hi/lo halves (Markidis decomposition)
__global__ __launch_bounds__(256) void k_wsplit(const float* __restrict__ W,
                                                unsigned short* __restrict__ whi,
                                                unsigned short* __restrict__ wlo,
                                                int n) {
  int i = blockIdx.x * 256 + threadIdx.x;
  if (i >= n) return;
  float w = W[i];
  unsigned short h = f2bf_rne(w);
  unsigned short l = f2bf_rne(w - bf2f(h));
  whi[i] = h; wlo[i] = l;
}

// ---- CSR build: histogram -> single-block scan -> scatter (col,val) pairs ----

__global__ __launch_bounds__(256) void k_hist(const int* __restrict__ rows,
                                              int* __restrict__ RO) {
  int e = blockIdx.x * 256 + threadIdx.x;
  if (e < NNZ) atomicAdd(&RO[rows[e]], 1);
}

// RO[0..N-1] holds counts on entry. On exit: RO[0..N] = exclusive scan (RO[N]=NNZ),
// C[r] = RO[r] (scatter cursors). Single block of 256 threads.
__global__ __launch_bounds__(256) void k_scan(int* __restrict__ RO, int* __restrict__ C) {
  __shared__ int part[256];
  const int T = 256;
  const int K = (N + T - 1) / T;  // 391
  int t = threadIdx.x;
  int lo = t * K;
  int hi = lo + K; if (hi > N) hi = N;
  int s = 0;
  for (int i = lo; i < hi; ++i) s += RO[i];
  part[t] = s;
  __syncthreads();
  if (t == 0) {
    int run = 0;
    for (int i = 0; i < T; ++i) { int v = part[i]; part[i] = run; run += v; }
  }
  __syncthreads();
  int run = part[t];
  for (int i = lo; i < hi; ++i) {
    int v = RO[i];
    RO[i] = run;
    C[i]  = run;
    run += v;
  }
  if (t == T - 1) RO[N] = run;  // == NNZ
}

__global__ __launch_bounds__(256) void k_scatter(const int* __restrict__ rows,
                                                 const int* __restrict__ cols,
                                                 const float* __restrict__ vals,
                                                 int* __restrict__ C,
                                                 int2* __restrict__ CV) {
  int e = blockIdx.x * 256 + threadIdx.x;
  if (e >= NNZ) return;
  int r = rows[e];
  int pos = atomicAdd(&C[r], 1);
  CV[pos] = make_int2(cols[e], __float_as_int(vals[e]));
}

// Row-parallel CSR SpMM, fused residual + dropout:
// B[r] = dropout(sum_e v_e * A[col_e] + A[r]).
// One wave per row; 64 lanes x 4 elems = full 256-wide row in registers. No atomics.
// BF=true: gathers from the bf16 shadow Abf (half the random-read bytes);
// residual + output stay f32.
template <bool BF>
__global__ __launch_bounds__(256) void k_spmm_csr(const int* __restrict__ RO,
                                                  const int2* __restrict__ CV,
                                                  const float* __restrict__ A,
                                                  const unsigned short* __restrict__ Abf,
                                                  float* __restrict__ B,
                                                  uint32_t k0, uint32_t k1) {
  int r = blockIdx.x * 4 + (threadIdx.x >> 6);
  if (r >= N) return;
  int c4 = (threadIdx.x & 63) * 4;
  int beg = RO[r], end = RO[r + 1];

  // residual + dropout mask computed up front so threefry VALU work overlaps gathers
  float4 res = *(const float4*)(A + (size_t)r * HID + c4);
  uint32_t e0 = (uint32_t)r * (uint32_t)HID + (uint32_t)c4;
  bool kp0 = keep_elem(k0, k1, e0 + 0u);
  bool kp1 = keep_elem(k0, k1, e0 + 1u);
  bool kp2 = keep_elem(k0, k1, e0 + 2u);
  bool kp3 = keep_elem(k0, k1, e0 + 3u);

  float ax = 0.f, ay = 0.f, az = 0.f, aw = 0.f;
  int i = beg;

  if (BF) {
    // 8-way unrolled: 8 independent 8B gathers in flight per iteration
#pragma unroll 1
    for (; i + 7 < end; i += 8) {
      int2 cv[8];
#pragma unroll
      for (int u = 0; u < 8; ++u) cv[u] = CV[i + u];
      us4 q[8];
#pragma unroll
      for (int u = 0; u < 8; ++u)
        q[u] = *(const us4*)(Abf + (size_t)cv[u].x * HID + c4);
#pragma unroll
      for (int u = 0; u < 8; ++u) {
        float v = __int_as_float(cv[u].y);
        ax = fmaf(v, bf2f(q[u][0]), ax);
        ay = fmaf(v, bf2f(q[u][1]), ay);
        az = fmaf(v, bf2f(q[u][2]), az);
        aw = fmaf(v, bf2f(q[u][3]), aw);
      }
    }
    for (; i < end; ++i) {
      int2 cv = CV[i];
      float v = __int_as_float(cv.y);
      us4 q = *(const us4*)(Abf + (size_t)cv.x * HID + c4);
      ax = fmaf(v, bf2f(q[0]), ax);
      ay = fmaf(v, bf2f(q[1]), ay);
      az = fmaf(v, bf2f(q[2]), az);
      aw = fmaf(v, bf2f(q[3]), aw);
    }
  } else {
#pragma unroll 1
    for (; i + 3 < end; i += 4) {
      int2 cv0 = CV[i + 0], cv1 = CV[i + 1], cv2 = CV[i + 2], cv3 = CV[i + 3];
      float4 x0 = *(const float4*)(A + (size_t)cv0.x * HID + c4);
      float4 x1 = *(const float4*)(A + (size_t)cv1.x * HID + c4);
      float4 x2 = *(const float4*)(A + (size_t)cv2.x * HID + c4);
      float4 x3 = *(const float4*)(A + (size_t)cv3.x * HID + c4);
      float v0 = __int_as_float(cv0.y), v1 = __int_as_float(cv1.y);
      float v2 = __int_as_float(cv2.y), v3 = __int_as_float(cv3.y);
      ax = fmaf(v0, x0.x, ax); ay = fmaf(v0, x0.y, ay);
      az = fmaf(v0, x0.z, az); aw = fmaf(v0, x0.w, aw);
      ax = fmaf(v1, x1.x, ax); ay = fmaf(v1, x1.y, ay);
      az = fmaf(v1, x1.z, az); aw = fmaf(v1, x1.w, aw);
      ax = fmaf(v2, x2.x, ax); ay = fmaf(v2, x2.y, ay);
      az = fmaf(v2, x2.z, az); aw = fmaf(v2, x2.w, aw);
      ax = fmaf(v3, x3.x, ax); ay = fmaf(v3, x3.y, ay);
      az = fmaf(v3, x3.z, az); aw = fmaf(v3, x3.w, aw);
    }
    for (; i < end; ++i) {
      int2 cv = CV[i];
      float v = __int_as_float(cv.y);
      float4 x = *(const float4*)(A + (size_t)cv.x * HID + c4);
      ax = fmaf(v, x.x, ax); ay = fmaf(v, x.y, ay);
      az = fmaf(v, x.z, az); aw = fmaf(v, x.w, aw);
    }
  }

  float4 o;
  o.x = kp0 ? (ax + res.x) / 0.9f : 0.0f;
  o.y = kp1 ? (ay + res.y) / 0.9f : 0.0f;
  o.z = kp2 ? (az + res.z) / 0.9f : 0.0f;
  o.w = kp3 ? (aw + res.w) / 0.9f : 0.0f;
  *(float4*)(B + (size_t)r * HID + c4) = o;
}

// ---- MFMA GEMM: out = leaky(M @ W^T + b) via split-bf16 (hi*hi + hi*lo + lo*hi) ----
// Block: 256 threads = 4 waves; 64-row tile; wave w covers cols [w*NC/4, (w+1)*NC/4).
// M staged to LDS as split bf16 in K-chunks of 128, XOR-swizzled against bank conflicts.
template <int NC, bool WRITE_F32>
__global__ __launch_bounds__(256) void k_gemm_mfma(const float* __restrict__ M,
                                                   const unsigned short* __restrict__ Whi,
                                                   const unsigned short* __restrict__ Wlo,
                                                   const float* __restrict__ bias,
                                                   float* __restrict__ Aout,
                                                   unsigned short* __restrict__ Abf,
                                                   float* __restrict__ out,
                                                   int colbase) {
  constexpr int WC = NC / 4;   // cols per wave (64 or 32)
  constexpr int CT = WC / 16;  // 16x16 col tiles per wave (4 or 2)
  __shared__ __align__(16) unsigned short mhi[64 * 128];
  __shared__ __align__(16) unsigned short mlo[64 * 128];

  const int tid  = threadIdx.x;
  const int wave = tid >> 6;
  const int lane = tid & 63;
  const int l15  = lane & 15;
  const int lhi  = lane >> 4;      // 0..3
  const int row0 = blockIdx.x * 64;
  const int wc0  = wave * WC;

  const f32x4 fzero = {0.f, 0.f, 0.f, 0.f};
  f32x4 acc[4][CT];
#pragma unroll
  for (int rt = 0; rt < 4; ++rt)
#pragma unroll
    for (int ct = 0; ct < CT; ++ct) acc[rt][ct] = fzero;

  const int tk = (tid & 31) * 4;   // staging k offset within chunk (0..124)
  const int tr = tid >> 5;         // staging row group 0..7

#pragma unroll 1
  for (int kc = 0; kc < HID; kc += 128) {
    __syncthreads();
    // stage M[row0:row0+64, kc:kc+128] -> split bf16, swizzled: elem k ^= (row&7)<<3
#pragma unroll
    for (int p = 0; p < 8; ++p) {
      int r = p * 8 + tr;
      int grow = row0 + r;
      float4 v = make_float4(0.f, 0.f, 0.f, 0.f);
      if (grow < N) v = *(const float4*)(M + (size_t)grow * HID + kc + tk);
      float vv[4] = {v.x, v.y, v.z, v.w};
      us4 h, l;
#pragma unroll
      for (int c = 0; c < 4; ++c) {
        unsigned short hh = f2bf_rne(vv[c]);
        h[c] = hh;
        l[c] = f2bf_rne(vv[c] - bf2f(hh));
      }
      int sidx = r * 128 + (tk ^ ((r & 7) << 3));
      *(us4*)(&mhi[sidx]) = h;
      *(us4*)(&mlo[sidx]) = l;
    }
    __syncthreads();

#pragma unroll
    for (int ks = 0; ks < 128; ks += 32) {
      const int kf = ks + lhi * 8;  // this lane's k offset within chunk
      // A fragments (hi/lo) for 4 row tiles from LDS
      bf16x8 ah[4], al[4];
#pragma unroll
      for (int rt = 0; rt < 4; ++rt) {
        int r = rt * 16 + l15;
        int idx = r * 128 + (kf ^ ((r & 7) << 3));
        ah[rt] = *(const bf16x8*)(&mhi[idx]);
        al[rt] = *(const bf16x8*)(&mlo[idx]);
      }
      // B fragments from global (L2-resident W) + MFMA
#pragma unroll
      for (int ct = 0; ct < CT; ++ct) {
        int col = wc0 + ct * 16 + l15;
        const unsigned short* wph = Whi + (size_t)col * HID + kc + kf;
        const unsigned short* wpl = Wlo + (size_t)col * HID + kc + kf;
        bf16x8 bh = *(const bf16x8*)wph;
        bf16x8 bl = *(const bf16x8*)wpl;
#pragma unroll
        for (int rt = 0; rt < 4; ++rt) {
          acc[rt][ct] = __builtin_amdgcn_mfma_f32_16x16x32_bf16(ah[rt], bh, acc[rt][ct], 0, 0, 0);
          acc[rt][ct] = __builtin_amdgcn_mfma_f32_16x16x32_bf16(ah[rt], bl, acc[rt][ct], 0, 0, 0);
          acc[rt][ct] = __builtin_amdgcn_mfma_f32_16x16x32_bf16(al[rt], bh, acc[rt][ct], 0, 0, 0);
        }
      }
    }
  }

  // epilogue: bias + leaky + store. C/D layout: col = lane&15, row = (lane>>4)*4 + reg.
#pragma unroll
  for (int ct = 0; ct < CT; ++ct) {
    int col = wc0 + ct * 16 + l15;
    float bv = bias[col];
#pragma unroll
    for (int rt = 0; rt < 4; ++rt) {
#pragma unroll
      for (int rg = 0; rg < 4; ++rg) {
        int grow = row0 + rt * 16 + lhi * 4 + rg;
        if (grow < N) {
          float v = acc[rt][ct][rg] + bv;
          v = (v >= 0.f) ? v : NEG_SLOPE * v;
          out[(size_t)grow * OUTW + colbase + col] = v;
          if (WRITE_F32) {
            Aout[(size_t)grow * HID + col] = v;
            if (Abf) Abf[(size_t)grow * HID + col] = f2bf_rne(v);
          }
        }
      }
    }
  }
}

// ---- fallback (old) path kernels, used if workspace too small ----
__global__ __launch_bounds__(256) void k_spmm(const int* __restrict__ rows,
                                              const int* __restrict__ cols,
                                              const float* __restrict__ vals,
                                              const float* __restrict__ A,
                                              float* __restrict__ B) {
  int e = blockIdx.x * 4 + (threadIdx.x >> 6);
  int lane = threadIdx.x & 63;
  if (e >= NNZ) return;
  int r = rows[e];
  int c = cols[e];
  float v = vals[e];
  float4 x = *(const float4*)(A + (size_t)c * HID + lane * 4);
  float* bp = B + (size_t)r * HID + lane * 4;
  unsafeAtomicAdd(bp + 0, v * x.x);
  unsafeAtomicAdd(bp + 1, v * x.y);
  unsafeAtomicAdd(bp + 2, v * x.z);
  unsafeAtomicAdd(bp + 3, v * x.w);
}

__global__ __launch_bounds__(256) void k_dropres(const float* __restrict__ A,
                                                 float* __restrict__ B,
                                                 uint32_t k0, uint32_t k1) {
  uint32_t e = blockIdx.x * 256 + threadIdx.x;
  if (e >= (uint32_t)N * HID) return;
  float m = B[e] + A[e];
  B[e] = keep_elem(k0, k1, e) ? (m / 0.9f) : 0.0f;
}

// old VALU GEMM (fallback only)
template <int NC, bool WRITE_F32>
__global__ __launch_bounds__(256) void k_gemm(const float* __restrict__ M,
                                              const float* __restrict__ W,
                                              const float* __restrict__ bias,
                                              float* __restrict__ Aout,
                                              float* __restrict__ out,
                                              int colbase) {
  constexpr int CG = NC / 4;    // col groups (64 or 32)
  constexpr int RG = 256 / CG;  // row groups (4 or 8)
  constexpr int RPT = 64 / RG;  // rows per thread (16 or 8)
  __shared__ float m_s[64][68];

  const int tid = threadIdx.x;
  const int j = tid % CG;
  const int rg = tid / CG;
  const int row0 = blockIdx.x * 64;
  const int r0 = rg * RPT;

  float acc[RPT][4];
#pragma unroll
  for (int i = 0; i < RPT; ++i)
#pragma unroll
    for (int c = 0; c < 4; ++c) acc[i][c] = 0.f;

  const int rr = tid >> 4;
  const int kk = (tid & 15) * 4;

#pragma unroll 1
  for (int kc = 0; kc < HID; kc += 64) {
    __syncthreads();
#pragma unroll
    for (int p = 0; p < 4; ++p) {
      int r = p * 16 + rr;
      int grow = row0 + r;
      float4 v = make_float4(0.f, 0.f, 0.f, 0.f);
      if (grow < N) v = *(const float4*)(M + (size_t)grow * HID + kc + kk);
      m_s[kk + 0][r] = v.x;
      m_s[kk + 1][r] = v.y;
      m_s[kk + 2][r] = v.z;
      m_s[kk + 3][r] = v.w;
    }
    __syncthreads();

#pragma unroll 1
    for (int ks = 0; ks < 64; ks += 8) {
      float4 wa[4], wb[4];
#pragma unroll
      for (int c = 0; c < 4; ++c) {
        const float* wp = W + (size_t)(4 * j + c) * HID + kc + ks;
        wa[c] = *(const float4*)(wp);
        wb[c] = *(const float4*)(wp + 4);
      }
#pragma unroll
      for (int q = 0; q < 8; ++q) {
        float wf[4];
#pragma unroll
        for (int c = 0; c < 4; ++c) {
          const float* wv = (q < 4) ? (const float*)&wa[c] : (const float*)&wb[c];
          wf[c] = wv[q & 3];
        }
        const float* ms = &m_s[ks + q][r0];
#pragma unroll
        for (int ii = 0; ii < RPT / 4; ++ii) {
          float4 mv = *(const float4*)(ms + ii * 4);
          const float mr[4] = {mv.x, mv.y, mv.z, mv.w};
#pragma unroll
          for (int t = 0; t < 4; ++t)
#pragma unroll
            for (int c = 0; c < 4; ++c)
              acc[ii * 4 + t][c] = fmaf(mr[t], wf[c], acc[ii * 4 + t][c]);
        }
      }
    }
  }

  float bv[4];
#pragma unroll
  for (int c = 0; c < 4; ++c) bv[c] = bias[4 * j + c];

#pragma unroll
  for (int i = 0; i < RPT; ++i) {
    int grow = row0 + r0 + i;
    if (grow < N) {
      float4 ov;
      float* ovp = (float*)&ov;
#pragma unroll
      for (int c = 0; c < 4; ++c) {
        float v = acc[i][c] + bv[c];
        ovp[c] = (v >= 0.f) ? v : NEG_SLOPE * v;
      }
      if (WRITE_F32)
        *(float4*)(Aout + (size_t)grow * HID + 4 * j) = ov;
      *(float4*)(out + (size_t)grow * OUTW + colbase + 4 * j) = ov;
    }
  }
}

// ---------------- host launcher ----------------
extern "C" void kernel_launch(void* const* d_in, const int* in_sizes, int n_in,
                              void* d_out, int out_size, void* d_ws, size_t ws_size,
                              hipStream_t stream) {
  (void)in_sizes; (void)n_in; (void)out_size;

  const int*   x_idx  = (const int*)d_in[0];
  const float* emb    = (const float*)d_in[1];
  const int*   g_rows = (const int*)d_in[2];
  const int*   g_cols = (const int*)d_in[3];
  const float* g_vals = (const float*)d_in[4];
  const float* W1 = (const float*)d_in[5];
  const float* b1 = (const float*)d_in[6];
  const float* W2 = (const float*)d_in[7];
  const float* b2 = (const float*)d_in[8];
  const float* W3 = (const float*)d_in[9];
  const float* b3 = (const float*)d_in[10];
  float* out = (float*)d_out;

  // ---- workspace layout ----
  float* A = (float*)d_ws;                 // current layer input h  [N,HID] f32
  float* B = A + (size_t)N * HID;          // spmm/m buffer          [N,HID] f32
  int*   RO = (int*)(B + (size_t)N * HID); // row offsets [N+1] (+pad)
  int*   C  = RO + (N + 2);                // scatter cursors [N]
  int2*  CV = (int2*)(C + N);              // packed (col,val) [NNZ], 8B aligned
  uintptr_t wsp = ((uintptr_t)(CV + NNZ) + 63) & ~(uintptr_t)63;
  unsigned short* Wh0 = (unsigned short*)wsp;      // split-bf16 weights
  unsigned short* Wl0 = Wh0 + 65536;
  unsigned short* Wh1 = Wl0 + 65536;
  unsigned short* Wl1 = Wh1 + 65536;
  unsigned short* Wh2 = Wl1 + 65536;               // W3 is [128,256]
  unsigned short* Wl2 = Wh2 + 32768;
  unsigned short* Abf = Wl2 + 32768;               // bf16 shadow of A [N,HID]
  const size_t NEED_CSR = (size_t)N * HID * 2 * sizeof(float)
                        + (size_t)(N + 2 + N) * sizeof(int)
                        + (size_t)NNZ * sizeof(int2)
                        + 64
                        + (size_t)(4 * 65536 + 2 * 32768) * sizeof(unsigned short);
  const size_t NEED_BF = NEED_CSR + (size_t)N * HID * sizeof(unsigned short);
  const bool use_csr = (ws_size >= NEED_CSR);
  const bool use_bf  = (ws_size >= NEED_BF);
  unsigned short* AbfArg = use_bf ? Abf : nullptr;

  // dropout keys: dk = split(key(42), 3), reproduced host-side
  uint32_t dk[3][2];
#if THREEFRY_PARTITIONABLE
  for (uint32_t i = 0; i < 3; ++i)
    threefry2x32(0u, 42u, 0u, i, dk[i][0], dk[i][1]);
#else
  {
    uint32_t a0, c0, a1, c1, a2, c2;
    threefry2x32(0u, 42u, 0u, 3u, a0, c0);
    threefry2x32(0u, 42u, 1u, 4u, a1, c1);
    threefry2x32(0u, 42u, 2u, 5u, a2, c2);
    dk[0][0] = a0; dk[0][1] = a1;
    dk[1][0] = a2; dk[1][1] = c0;
    dk[2][0] = c1; dk[2][1] = c2;
  }
#endif

  const int gemm_blocks = (N + 63) / 64;   // 1563

  k_gather<<<(N * 64) / 256, 256, 0, stream>>>(x_idx, emb, A, AbfArg, out);

  const float* Ws[3] = {W1, W2, W3};
  const float* bs[3] = {b1, b2, b3};
  unsigned short* Whs[3] = {Wh0, Wh1, Wh2};
  unsigned short* Wls[3] = {Wl0, Wl1, Wl2};

  if (use_csr) {
    // build CSR once; the graph is reused by all 3 SpMMs
    k_zero_i<<<(N + 2 + 255) / 256, 256, 0, stream>>>(RO, N + 2);
    k_hist<<<(NNZ + 255) / 256, 256, 0, stream>>>(g_rows, RO);
    k_scan<<<1, 256, 0, stream>>>(RO, C);
    k_scatter<<<(NNZ + 255) / 256, 256, 0, stream>>>(g_rows, g_cols, g_vals, C, CV);
    // split weights to bf16 hi/lo once
    k_wsplit<<<(65536 + 255) / 256, 256, 0, stream>>>(W1, Wh0, Wl0, 65536);
    k_wsplit<<<(65536 + 255) / 256, 256, 0, stream>>>(W2, Wh1, Wl1, 65536);
    k_wsplit<<<(32768 + 255) / 256, 256, 0, stream>>>(W3, Wh2, Wl2, 32768);
  }

  for (int l = 0; l < 3; ++l) {
    if (use_csr) {
      if (use_bf)
        k_spmm_csr<true><<<(N + 3) / 4, 256, 0, stream>>>(RO, CV, A, Abf, B, dk[l][0], dk[l][1]);
      else
        k_spmm_csr<false><<<(N + 3) / 4, 256, 0, stream>>>(RO, CV, A, nullptr, B, dk[l][0], dk[l][1]);
      if (l < 2)
        k_gemm_mfma<HID, true><<<gemm_blocks, 256, 0, stream>>>(B, Whs[l], Wls[l], bs[l], A, AbfArg, out, HID * (l + 1));
      else
        k_gemm_mfma<IEMB, false><<<gemm_blocks, 256, 0, stream>>>(B, Whs[2], Wls[2], bs[2], nullptr, nullptr, out, 3 * HID);
    } else {
      k_zero<<<(N * HID / 4 + 255) / 256, 256, 0, stream>>>((float4*)B, N * HID / 4);
      k_spmm<<<NNZ / 4, 256, 0, stream>>>(g_rows, g_cols, g_vals, A, B);
      k_dropres<<<(N * HID) / 256, 256, 0, stream>>>(A, B, dk[l][0], dk[l][1]);
      if (l < 2)
        k_gemm<HID, true><<<gemm_blocks, 256, 0, stream>>>(B, Ws[l], bs[l], A, out, HID * (l + 1));
      else
        k_gemm<IEMB, false><<<gemm_blocks, 256, 0, stream>>>(B, Ws[2], bs[2], nullptr, out, 3 * HID);
    }
  }
}

// Round 5
// 2240.649 us; speedup vs baseline: 14.8271x; 1.0164x over previous
//
#include <hip/hip_runtime.h>
#include <stdint.h>
#include <stddef.h>

// ---------------- problem constants ----------------
static constexpr int N    = 100000;
static constexpr int HID  = 256;
static constexpr int IEMB = 128;
static constexpr int NNZ  = 3200000;
static constexpr int OUTW = 3 * HID + IEMB;  // 896
static constexpr float NEG_SLOPE = 0.2f;

// JAX threefry variant: 1 = partitionable (default in JAX >= 0.5.0), 0 = original
#define THREEFRY_PARTITIONABLE 1

typedef __attribute__((ext_vector_type(8))) short bf16x8;
typedef __attribute__((ext_vector_type(4))) float f32x4;
typedef __attribute__((ext_vector_type(4))) unsigned short us4;

// ---------------- threefry2x32 (JAX-compatible) ----------------
__host__ __device__ inline uint32_t rotl32(uint32_t v, int r) {
  return (v << r) | (v >> (32 - r));
}

__host__ __device__ inline void threefry2x32(uint32_t k0, uint32_t k1,
                                             uint32_t x0, uint32_t x1,
                                             uint32_t& o0, uint32_t& o1) {
  const uint32_t k2 = k0 ^ k1 ^ 0x1BD11BDAu;
  x0 += k0; x1 += k1;
  // rounds 1-4
  x0 += x1; x1 = rotl32(x1, 13); x1 ^= x0;
  x0 += x1; x1 = rotl32(x1, 15); x1 ^= x0;
  x0 += x1; x1 = rotl32(x1, 26); x1 ^= x0;
  x0 += x1; x1 = rotl32(x1,  6); x1 ^= x0;
  x0 += k1; x1 += k2 + 1u;
  // rounds 5-8
  x0 += x1; x1 = rotl32(x1, 17); x1 ^= x0;
  x0 += x1; x1 = rotl32(x1, 29); x1 ^= x0;
  x0 += x1; x1 = rotl32(x1, 16); x1 ^= x0;
  x0 += x1; x1 = rotl32(x1, 24); x1 ^= x0;
  x0 += k2; x1 += k0 + 2u;
  // rounds 9-12
  x0 += x1; x1 = rotl32(x1, 13); x1 ^= x0;
  x0 += x1; x1 = rotl32(x1, 15); x1 ^= x0;
  x0 += x1; x1 = rotl32(x1, 26); x1 ^= x0;
  x0 += x1; x1 = rotl32(x1,  6); x1 ^= x0;
  x0 += k0; x1 += k1 + 3u;
  // rounds 13-16
  x0 += x1; x1 = rotl32(x1, 17); x1 ^= x0;
  x0 += x1; x1 = rotl32(x1, 29); x1 ^= x0;
  x0 += x1; x1 = rotl32(x1, 16); x1 ^= x0;
  x0 += x1; x1 = rotl32(x1, 24); x1 ^= x0;
  x0 += k1; x1 += k2 + 4u;
  // rounds 17-20
  x0 += x1; x1 = rotl32(x1, 13); x1 ^= x0;
  x0 += x1; x1 = rotl32(x1, 15); x1 ^= x0;
  x0 += x1; x1 = rotl32(x1, 26); x1 ^= x0;
  x0 += x1; x1 = rotl32(x1,  6); x1 ^= x0;
  x0 += k2; x1 += k0 + 5u;
  o0 = x0; o1 = x1;
}

// keep-mask for flat element index e of a [N,HID] dropout draw under key (k0,k1)
__device__ inline bool keep_elem(uint32_t k0, uint32_t k1, uint32_t e) {
  uint32_t o0, o1, bits;
#if THREEFRY_PARTITIONABLE
  threefry2x32(k0, k1, 0u, e, o0, o1);   // counter = 64-bit flat index (hi=0, lo=e)
  bits = o0 ^ o1;                        // 32-bit draw folds the two output words
#else
  const uint32_t H = (uint32_t)(N) * (uint32_t)(HID) / 2u;  // 12,800,000
  if (e < H) { threefry2x32(k0, k1, e, e + H, o0, o1); bits = o0; }
  else       { threefry2x32(k0, k1, e - H, e, o0, o1); bits = o1; }
#endif
  float u = __uint_as_float((bits >> 9) | 0x3f800000u) - 1.0f;  // [0,1)
  return u < 0.9f;  // bernoulli(keep=0.9): uniform < p
}

// ---------------- bf16 helpers ----------------
__device__ inline unsigned short f2bf_rne(float x) {
  uint32_t u = __float_as_uint(x);
  uint32_t r = (u + 0x7FFFu + ((u >> 16) & 1u)) >> 16;
  return (unsigned short)r;
}
__device__ inline float bf2f(unsigned short h) {
  return __uint_as_float(((uint32_t)h) << 16);
}

// ---------------- kernels (all float32) ----------------

// x = embed[x_idx]; write f32 copy to A (stride HID), bf16 copy to Abf, and out cols [0,256)
__global__ __launch_bounds__(256) void k_gather(const int* __restrict__ xidx,
                                                const float* __restrict__ emb,
                                                float* __restrict__ A,
                                                unsigned short* __restrict__ Abf,
                                                float* __restrict__ out) {
  int t = blockIdx.x * 256 + threadIdx.x;          // over N*64 chunks of 4 elems
  int n = t >> 6;
  int c4 = (t & 63) * 4;
  if (n >= N) return;
  int src = xidx[n];
  float4 v = *(const float4*)(emb + (size_t)src * HID + c4);
  *(float4*)(out + (size_t)n * OUTW + c4) = v;
  *(float4*)(A + (size_t)n * HID + c4) = v;
  if (Abf) {
    us4 q;
    q[0] = f2bf_rne(v.x); q[1] = f2bf_rne(v.y);
    q[2] = f2bf_rne(v.z); q[3] = f2bf_rne(v.w);
    *(us4*)(Abf + (size_t)n * HID + c4) = q;
  }
}

__global__ __launch_bounds__(256) void k_zero(float4* __restrict__ p, int n4) {
  int i = blockIdx.x * 256 + threadIdx.x;
  if (i < n4) p[i] = make_float4(0.f, 0.f, 0.f, 0.f);
}

__global__ __launch_bounds__(256) void k_zero_i(int* __restrict__ p, int n) {
  int i = blockIdx.x * 256 + threadIdx.x;
  if (i < n) p[i] = 0;
}

// split W into bf16 hi/lo halves, stored in MFMA-fragment-flat order:
// frag index t = (kb*nct + c16)*64 + lane  maps to
//   col = c16*16 + (lane&15), k = kb*32 + (lane>>4)*8 + j  (j = 0..7)
// so a wave's fragment load in the GEMM is one contiguous 1KB read.
__global__ __launch_bounds__(256) void k_wsplit_frag(const float* __restrict__ W,
                                                     unsigned short* __restrict__ whi,
                                                     unsigned short* __restrict__ wlo,
                                                     int nct) {
  int t = blockIdx.x * 256 + threadIdx.x;
  int total = 8 * nct * 64;            // NKB(=8) * nct * 64 lanes
  if (t >= total) return;
  int kb   = t / (nct * 64);
  int rem  = t - kb * nct * 64;
  int c16  = rem >> 6;
  int lane = rem & 63;
  int col  = c16 * 16 + (lane & 15);
  int kbase = kb * 32 + ((lane >> 4) << 3);
  const float* wp = W + (size_t)col * HID + kbase;
  us4 h0, h1, l0, l1;
#pragma unroll
  for (int j = 0; j < 4; ++j) {
    float w = wp[j];
    unsigned short hh = f2bf_rne(w);
    h0[j] = hh; l0[j] = f2bf_rne(w - bf2f(hh));
  }
#pragma unroll
  for (int j = 0; j < 4; ++j) {
    float w = wp[4 + j];
    unsigned short hh = f2bf_rne(w);
    h1[j] = hh; l1[j] = f2bf_rne(w - bf2f(hh));
  }
  *(us4*)(whi + (size_t)t * 8)     = h0;
  *(us4*)(whi + (size_t)t * 8 + 4) = h1;
  *(us4*)(wlo + (size_t)t * 8)     = l0;
  *(us4*)(wlo + (size_t)t * 8 + 4) = l1;
}

// ---- CSR build: histogram -> single-block scan -> scatter (col,val) pairs ----

__global__ __launch_bounds__(256) void k_hist(const int* __restrict__ rows,
                                              int* __restrict__ RO) {
  int e = blockIdx.x * 256 + threadIdx.x;
  if (e < NNZ) atomicAdd(&RO[rows[e]], 1);
}

// RO[0..N-1] holds counts on entry. On exit: RO[0..N] = exclusive scan (RO[N]=NNZ),
// C[r] = RO[r] (scatter cursors). Single block of 256 threads.
__global__ __launch_bounds__(256) void k_scan(int* __restrict__ RO, int* __restrict__ C) {
  __shared__ int part[256];
  const int T = 256;
  const int K = (N + T - 1) / T;  // 391
  int t = threadIdx.x;
  int lo = t * K;
  int hi = lo + K; if (hi > N) hi = N;
  int s = 0;
  for (int i = lo; i < hi; ++i) s += RO[i];
  part[t] = s;
  __syncthreads();
  if (t == 0) {
    int run = 0;
    for (int i = 0; i < T; ++i) { int v = part[i]; part[i] = run; run += v; }
  }
  __syncthreads();
  int run = part[t];
  for (int i = lo; i < hi; ++i) {
    int v = RO[i];
    RO[i] = run;
    C[i]  = run;
    run += v;
  }
  if (t == T - 1) RO[N] = run;  // == NNZ
}

__global__ __launch_bounds__(256) void k_scatter(const int* __restrict__ rows,
                                                 const int* __restrict__ cols,
                                                 const float* __restrict__ vals,
                                                 int* __restrict__ C,
                                                 int2* __restrict__ CV) {
  int e = blockIdx.x * 256 + threadIdx.x;
  if (e >= NNZ) return;
  int r = rows[e];
  int pos = atomicAdd(&C[r], 1);
  CV[pos] = make_int2(cols[e], __float_as_int(vals[e]));
}

// Row-parallel CSR SpMM, fused residual + dropout:
// B[r] = dropout(sum_e v_e * A[col_e] + A[r]).
// One wave per row; 64 lanes x 4 elems = full 256-wide row in registers. No atomics.
// BF=true: gathers from the bf16 shadow Abf (half the random-read bytes);
// residual + output stay f32.
template <bool BF>
__global__ __launch_bounds__(256) void k_spmm_csr(const int* __restrict__ RO,
                                                  const int2* __restrict__ CV,
                                                  const float* __restrict__ A,
                                                  const unsigned short* __restrict__ Abf,
                                                  float* __restrict__ B,
                                                  uint32_t k0, uint32_t k1) {
  int r = blockIdx.x * 4 + (threadIdx.x >> 6);
  if (r >= N) return;
  int c4 = (threadIdx.x & 63) * 4;
  int beg = RO[r], end = RO[r + 1];

  // residual + dropout mask computed up front so threefry VALU work overlaps gathers
  float4 res = *(const float4*)(A + (size_t)r * HID + c4);
  uint32_t e0 = (uint32_t)r * (uint32_t)HID + (uint32_t)c4;
  bool kp0 = keep_elem(k0, k1, e0 + 0u);
  bool kp1 = keep_elem(k0, k1, e0 + 1u);
  bool kp2 = keep_elem(k0, k1, e0 + 2u);
  bool kp3 = keep_elem(k0, k1, e0 + 3u);

  float ax = 0.f, ay = 0.f, az = 0.f, aw = 0.f;
  int i = beg;

  if (BF) {
    // 8-way unrolled: 8 independent 8B gathers in flight per iteration
#pragma unroll 1
    for (; i + 7 < end; i += 8) {
      int2 cv[8];
#pragma unroll
      for (int u = 0; u < 8; ++u) cv[u] = CV[i + u];
      us4 q[8];
#pragma unroll
      for (int u = 0; u < 8; ++u)
        q[u] = *(const us4*)(Abf + (size_t)cv[u].x * HID + c4);
#pragma unroll
      for (int u = 0; u < 8; ++u) {
        float v = __int_as_float(cv[u].y);
        ax = fmaf(v, bf2f(q[u][0]), ax);
        ay = fmaf(v, bf2f(q[u][1]), ay);
        az = fmaf(v, bf2f(q[u][2]), az);
        aw = fmaf(v, bf2f(q[u][3]), aw);
      }
    }
    for (; i < end; ++i) {
      int2 cv = CV[i];
      float v = __int_as_float(cv.y);
      us4 q = *(const us4*)(Abf + (size_t)cv.x * HID + c4);
      ax = fmaf(v, bf2f(q[0]), ax);
      ay = fmaf(v, bf2f(q[1]), ay);
      az = fmaf(v, bf2f(q[2]), az);
      aw = fmaf(v, bf2f(q[3]), aw);
    }
  } else {
#pragma unroll 1
    for (; i + 3 < end; i += 4) {
      int2 cv0 = CV[i + 0], cv1 = CV[i + 1], cv2 = CV[i + 2], cv3 = CV[i + 3];
      float4 x0 = *(const float4*)(A + (size_t)cv0.x * HID + c4);
      float4 x1 = *(const float4*)(A + (size_t)cv1.x * HID + c4);
      float4 x2 = *(const float4*)(A + (size_t)cv2.x * HID + c4);
      float4 x3 = *(const float4*)(A + (size_t)cv3.x * HID + c4);
      float v0 = __int_as_float(cv0.y), v1 = __int_as_float(cv1.y);
      float v2 = __int_as_float(cv2.y), v3 = __int_as_float(cv3.y);
      ax = fmaf(v0, x0.x, ax); ay = fmaf(v0, x0.y, ay);
      az = fmaf(v0, x0.z, az); aw = fmaf(v0, x0.w, aw);
      ax = fmaf(v1, x1.x, ax); ay = fmaf(v1, x1.y, ay);
      az = fmaf(v1, x1.z, az); aw = fmaf(v1, x1.w, aw);
      ax = fmaf(v2, x2.x, ax); ay = fmaf(v2, x2.y, ay);
      az = fmaf(v2, x2.z, az); aw = fmaf(v2, x2.w, aw);
      ax = fmaf(v3, x3.x, ax); ay = fmaf(v3, x3.y, ay);
      az = fmaf(v3, x3.z, az); aw = fmaf(v3, x3.w, aw);
    }
    for (; i < end; ++i) {
      int2 cv = CV[i];
      float v = __int_as_float(cv.y);
      float4 x = *(const float4*)(A + (size_t)cv.x * HID + c4);
      ax = fmaf(v, x.x, ax); ay = fmaf(v, x.y, ay);
      az = fmaf(v, x.z, az); aw = fmaf(v, x.w, aw);
    }
  }

  float4 o;
  o.x = kp0 ? (ax + res.x) / 0.9f : 0.0f;
  o.y = kp1 ? (ay + res.y) / 0.9f : 0.0f;
  o.z = kp2 ? (az + res.z) / 0.9f : 0.0f;
  o.w = kp3 ? (aw + res.w) / 0.9f : 0.0f;
  *(float4*)(B + (size_t)r * HID + c4) = o;
}

// ---- MFMA GEMM: out = leaky(M @ W^T + b) via split-bf16 (hi*hi + hi*lo + lo*hi) ----
// Block: 256 threads = 4 waves; 64-row tile; wave w covers cols [w*NC/4, (w+1)*NC/4).
// M staged to LDS as split bf16 in K-chunks of 128, XOR-swizzled against bank conflicts.
// Operand order: mfma(W_frag, M_frag, acc) so D has lane&15 = M-row and
// (lane>>4)*4+reg = 4 consecutive W-cols -> float4 epilogue stores.
// W is consumed from the fragment-flat layout written by k_wsplit_frag (1KB coalesced loads).
template <int NC, bool WRITE_F32>
__global__ __launch_bounds__(256) void k_gemm_mfma(const float* __restrict__ M,
                                                   const unsigned short* __restrict__ Whf,
                                                   const unsigned short* __restrict__ Wlf,
                                                   const float* __restrict__ bias,
                                                   float* __restrict__ Aout,
                                                   unsigned short* __restrict__ Abf,
                                                   float* __restrict__ out,
                                                   int colbase) {
  constexpr int WC  = NC / 4;   // cols per wave (64 or 32)
  constexpr int CT  = WC / 16;  // 16x16 col tiles per wave (4 or 2)
  constexpr int NCT = NC / 16;  // total col tiles (16 or 8)
  __shared__ __align__(16) unsigned short mhi[64 * 128];
  __shared__ __align__(16) unsigned short mlo[64 * 128];

  const int tid  = threadIdx.x;
  const int wave = tid >> 6;
  const int lane = tid & 63;
  const int l15  = lane & 15;
  const int lhi  = lane >> 4;      // 0..3
  const int row0 = blockIdx.x * 64;
  const int wc0  = wave * WC;

  const f32x4 fzero = {0.f, 0.f, 0.f, 0.f};
  f32x4 acc[4][CT];
#pragma unroll
  for (int rt = 0; rt < 4; ++rt)
#pragma unroll
    for (int ct = 0; ct < CT; ++ct) acc[rt][ct] = fzero;

  const int tk = (tid & 31) * 4;   // staging k offset within chunk (0..124)
  const int tr = tid >> 5;         // staging row group 0..7

#pragma unroll 1
  for (int kc = 0; kc < HID; kc += 128) {
    __syncthreads();
    // stage M[row0:row0+64, kc:kc+128] -> split bf16, swizzled: elem k ^= (row&7)<<3
#pragma unroll
    for (int p = 0; p < 8; ++p) {
      int r = p * 8 + tr;
      int grow = row0 + r;
      float4 v = make_float4(0.f, 0.f, 0.f, 0.f);
      if (grow < N) v = *(const float4*)(M + (size_t)grow * HID + kc + tk);
      float vv[4] = {v.x, v.y, v.z, v.w};
      us4 h, l;
#pragma unroll
      for (int c = 0; c < 4; ++c) {
        unsigned short hh = f2bf_rne(vv[c]);
        h[c] = hh;
        l[c] = f2bf_rne(vv[c] - bf2f(hh));
      }
      int sidx = r * 128 + (tk ^ ((r & 7) << 3));
      *(us4*)(&mhi[sidx]) = h;
      *(us4*)(&mlo[sidx]) = l;
    }
    __syncthreads();

#pragma unroll
    for (int ks = 0; ks < 128; ks += 32) {
      const int kf = ks + lhi * 8;  // this lane's k offset within chunk
      // M fragments (hi/lo) for 4 row tiles from LDS (B-operand: idx = M-row = l15)
      bf16x8 mh[4], ml[4];
#pragma unroll
      for (int rt = 0; rt < 4; ++rt) {
        int r = rt * 16 + l15;
        int idx = r * 128 + (kf ^ ((r & 7) << 3));
        mh[rt] = *(const bf16x8*)(&mhi[idx]);
        ml[rt] = *(const bf16x8*)(&mlo[idx]);
      }
      // W fragments from fragment-flat global layout (1KB coalesced per load)
      const int kbg = (kc + ks) >> 5;
      bf16x8 wh[CT], wl[CT];
#pragma unroll
      for (int ct = 0; ct < CT; ++ct) {
        size_t wfo = ((size_t)(kbg * NCT + wave * CT + ct) * 64 + lane) * 8;
        wh[ct] = *(const bf16x8*)(Whf + wfo);
        wl[ct] = *(const bf16x8*)(Wlf + wfo);
      }
#pragma unroll
      for (int ct = 0; ct < CT; ++ct) {
#pragma unroll
        for (int rt = 0; rt < 4; ++rt) {
          acc[rt][ct] = __builtin_amdgcn_mfma_f32_16x16x32_bf16(wh[ct], mh[rt], acc[rt][ct], 0, 0, 0);
          acc[rt][ct] = __builtin_amdgcn_mfma_f32_16x16x32_bf16(wh[ct], ml[rt], acc[rt][ct], 0, 0, 0);
          acc[rt][ct] = __builtin_amdgcn_mfma_f32_16x16x32_bf16(wl[ct], mh[rt], acc[rt][ct], 0, 0, 0);
        }
      }
    }
  }

  // epilogue: D layout (swapped operands): M-row = lane&15, W-col = (lane>>4)*4 + reg.
  // Each acc quad is 4 consecutive output cols of one row -> float4 stores.
#pragma unroll
  for (int ct = 0; ct < CT; ++ct) {
    int colq = wc0 + ct * 16 + lhi * 4;
    float4 bv = *(const float4*)(bias + colq);
    const float* bvp = (const float*)&bv;
#pragma unroll
    for (int rt = 0; rt < 4; ++rt) {
      int grow = row0 + rt * 16 + l15;
      if (grow < N) {
        float4 ov;
        float* ovp = (float*)&ov;
#pragma unroll
        for (int c = 0; c < 4; ++c) {
          float v = acc[rt][ct][c] + bvp[c];
          ovp[c] = (v >= 0.f) ? v : NEG_SLOPE * v;
        }
        *(float4*)(out + (size_t)grow * OUTW + colbase + colq) = ov;
        if (WRITE_F32) {
          *(float4*)(Aout + (size_t)grow * HID + colq) = ov;
          if (Abf) {
            us4 q;
            q[0] = f2bf_rne(ov.x); q[1] = f2bf_rne(ov.y);
            q[2] = f2bf_rne(ov.z); q[3] = f2bf_rne(ov.w);
            *(us4*)(Abf + (size_t)grow * HID + colq) = q;
          }
        }
      }
    }
  }
}

// ---- fallback (old) path kernels, used if workspace too small ----
__global__ __launch_bounds__(256) void k_spmm(const int* __restrict__ rows,
                                              const int* __restrict__ cols,
                                              const float* __restrict__ vals,
                                              const float* __restrict__ A,
                                              float* __restrict__ B) {
  int e = blockIdx.x * 4 + (threadIdx.x >> 6);
  int lane = threadIdx.x & 63;
  if (e >= NNZ) return;
  int r = rows[e];
  int c = cols[e];
  float v = vals[e];
  float4 x = *(const float4*)(A + (size_t)c * HID + lane * 4);
  float* bp = B + (size_t)r * HID + lane * 4;
  unsafeAtomicAdd(bp + 0, v * x.x);
  unsafeAtomicAdd(bp + 1, v * x.y);
  unsafeAtomicAdd(bp + 2, v * x.z);
  unsafeAtomicAdd(bp + 3, v * x.w);
}

__global__ __launch_bounds__(256) void k_dropres(const float* __restrict__ A,
                                                 float* __restrict__ B,
                                                 uint32_t k0, uint32_t k1) {
  uint32_t e = blockIdx.x * 256 + threadIdx.x;
  if (e >= (uint32_t)N * HID) return;
  float m = B[e] + A[e];
  B[e] = keep_elem(k0, k1, e) ? (m / 0.9f) : 0.0f;
}

// old VALU GEMM (fallback only)
template <int NC, bool WRITE_F32>
__global__ __launch_bounds__(256) void k_gemm(const float* __restrict__ M,
                                              const float* __restrict__ W,
                                              const float* __restrict__ bias,
                                              float* __restrict__ Aout,
                                              float* __restrict__ out,
                                              int colbase) {
  constexpr int CG = NC / 4;    // col groups (64 or 32)
  constexpr int RG = 256 / CG;  // row groups (4 or 8)
  constexpr int RPT = 64 / RG;  // rows per thread (16 or 8)
  __shared__ float m_s[64][68];

  const int tid = threadIdx.x;
  const int j = tid % CG;
  const int rg = tid / CG;
  const int row0 = blockIdx.x * 64;
  const int r0 = rg * RPT;

  float acc[RPT][4];
#pragma unroll
  for (int i = 0; i < RPT; ++i)
#pragma unroll
    for (int c = 0; c < 4; ++c) acc[i][c] = 0.f;

  const int rr = tid >> 4;
  const int kk = (tid & 15) * 4;

#pragma unroll 1
  for (int kc = 0; kc < HID; kc += 64) {
    __syncthreads();
#pragma unroll
    for (int p = 0; p < 4; ++p) {
      int r = p * 16 + rr;
      int grow = row0 + r;
      float4 v = make_float4(0.f, 0.f, 0.f, 0.f);
      if (grow < N) v = *(const float4*)(M + (size_t)grow * HID + kc + kk);
      m_s[kk + 0][r] = v.x;
      m_s[kk + 1][r] = v.y;
      m_s[kk + 2][r] = v.z;
      m_s[kk + 3][r] = v.w;
    }
    __syncthreads();

#pragma unroll 1
    for (int ks = 0; ks < 64; ks += 8) {
      float4 wa[4], wb[4];
#pragma unroll
      for (int c = 0; c < 4; ++c) {
        const float* wp = W + (size_t)(4 * j + c) * HID + kc + ks;
        wa[c] = *(const float4*)(wp);
        wb[c] = *(const float4*)(wp + 4);
      }
#pragma unroll
      for (int q = 0; q < 8; ++q) {
        float wf[4];
#pragma unroll
        for (int c = 0; c < 4; ++c) {
          const float* wv = (q < 4) ? (const float*)&wa[c] : (const float*)&wb[c];
          wf[c] = wv[q & 3];
        }
        const float* ms = &m_s[ks + q][r0];
#pragma unroll
        for (int ii = 0; ii < RPT / 4; ++ii) {
          float4 mv = *(const float4*)(ms + ii * 4);
          const float mr[4] = {mv.x, mv.y, mv.z, mv.w};
#pragma unroll
          for (int t = 0; t < 4; ++t)
#pragma unroll
            for (int c = 0; c < 4; ++c)
              acc[ii * 4 + t][c] = fmaf(mr[t], wf[c], acc[ii * 4 + t][c]);
        }
      }
    }
  }

  float bv[4];
#pragma unroll
  for (int c = 0; c < 4; ++c) bv[c] = bias[4 * j + c];

#pragma unroll
  for (int i = 0; i < RPT; ++i) {
    int grow = row0 + r0 + i;
    if (grow < N) {
      float4 ov;
      float* ovp = (float*)&ov;
#pragma unroll
      for (int c = 0; c < 4; ++c) {
        float v = acc[i][c] + bv[c];
        ovp[c] = (v >= 0.f) ? v : NEG_SLOPE * v;
      }
      if (WRITE_F32)
        *(float4*)(Aout + (size_t)grow * HID + 4 * j) = ov;
      *(float4*)(out + (size_t)grow * OUTW + colbase + 4 * j) = ov;
    }
  }
}

// ---------------- host launcher ----------------
extern "C" void kernel_launch(void* const* d_in, const int* in_sizes, int n_in,
                              void* d_out, int out_size, void* d_ws, size_t ws_size,
                              hipStream_t stream) {
  (void)in_sizes; (void)n_in; (void)out_size;

  const int*   x_idx  = (const int*)d_in[0];
  const float* emb    = (const float*)d_in[1];
  const int*   g_rows = (const int*)d_in[2];
  const int*   g_cols = (const int*)d_in[3];
  const float* g_vals = (const float*)d_in[4];
  const float* W1 = (const float*)d_in[5];
  const float* b1 = (const float*)d_in[6];
  const float* W2 = (const float*)d_in[7];
  const float* b2 = (const float*)d_in[8];
  const float* W3 = (const float*)d_in[9];
  const float* b3 = (const float*)d_in[10];
  float* out = (float*)d_out;

  // ---- workspace layout ----
  float* A = (float*)d_ws;                 // current layer input h  [N,HID] f32
  float* B = A + (size_t)N * HID;          // spmm/m buffer          [N,HID] f32
  int*   RO = (int*)(B + (size_t)N * HID); // row offsets [N+1] (+pad)
  int*   C  = RO + (N + 2);                // scatter cursors [N]
  int2*  CV = (int2*)(C + N);              // packed (col,val) [NNZ], 8B aligned
  uintptr_t wsp = ((uintptr_t)(CV + NNZ) + 63) & ~(uintptr_t)63;
  unsigned short* Wh0 = (unsigned short*)wsp;      // split-bf16 weights (fragment-flat)
  unsigned short* Wl0 = Wh0 + 65536;
  unsigned short* Wh1 = Wl0 + 65536;
  unsigned short* Wl1 = Wh1 + 65536;
  unsigned short* Wh2 = Wl1 + 65536;               // W3 is [128,256]
  unsigned short* Wl2 = Wh2 + 32768;
  unsigned short* Abf = Wl2 + 32768;               // bf16 shadow of A [N,HID]
  const size_t NEED_CSR = (size_t)N * HID * 2 * sizeof(float)
                        + (size_t)(N + 2 + N) * sizeof(int)
                        + (size_t)NNZ * sizeof(int2)
                        + 64
                        + (size_t)(4 * 65536 + 2 * 32768) * sizeof(unsigned short);
  const size_t NEED_BF = NEED_CSR + (size_t)N * HID * sizeof(unsigned short);
  const bool use_csr = (ws_size >= NEED_CSR);
  const bool use_bf  = (ws_size >= NEED_BF);
  unsigned short* AbfArg = use_bf ? Abf : nullptr;

  // dropout keys: dk = split(key(42), 3), reproduced host-side
  uint32_t dk[3][2];
#if THREEFRY_PARTITIONABLE
  for (uint32_t i = 0; i < 3; ++i)
    threefry2x32(0u, 42u, 0u, i, dk[i][0], dk[i][1]);
#else
  {
    uint32_t a0, c0, a1, c1, a2, c2;
    threefry2x32(0u, 42u, 0u, 3u, a0, c0);
    threefry2x32(0u, 42u, 1u, 4u, a1, c1);
    threefry2x32(0u, 42u, 2u, 5u, a2, c2);
    dk[0][0] = a0; dk[0][1] = a1;
    dk[1][0] = a2; dk[1][1] = c0;
    dk[2][0] = c1; dk[2][1] = c2;
  }
#endif

  const int gemm_blocks = (N + 63) / 64;   // 1563

  k_gather<<<(N * 64) / 256, 256, 0, stream>>>(x_idx, emb, A, AbfArg, out);

  const float* Ws[3] = {W1, W2, W3};
  const float* bs[3] = {b1, b2, b3};
  unsigned short* Whs[3] = {Wh0, Wh1, Wh2};
  unsigned short* Wls[3] = {Wl0, Wl1, Wl2};

  if (use_csr) {
    // build CSR once; the graph is reused by all 3 SpMMs
    k_zero_i<<<(N + 2 + 255) / 256, 256, 0, stream>>>(RO, N + 2);
    k_hist<<<(NNZ + 255) / 256, 256, 0, stream>>>(g_rows, RO);
    k_scan<<<1, 256, 0, stream>>>(RO, C);
    k_scatter<<<(NNZ + 255) / 256, 256, 0, stream>>>(g_rows, g_cols, g_vals, C, CV);
    // split weights to bf16 hi/lo once, in MFMA fragment-flat layout
    k_wsplit_frag<<<(8 * 16 * 64 + 255) / 256, 256, 0, stream>>>(W1, Wh0, Wl0, 16);
    k_wsplit_frag<<<(8 * 16 * 64 + 255) / 256, 256, 0, stream>>>(W2, Wh1, Wl1, 16);
    k_wsplit_frag<<<(8 * 8 * 64 + 255) / 256, 256, 0, stream>>>(W3, Wh2, Wl2, 8);
  }

  for (int l = 0; l < 3; ++l) {
    if (use_csr) {
      if (use_bf)
        k_spmm_csr<true><<<(N + 3) / 4, 256, 0, stream>>>(RO, CV, A, Abf, B, dk[l][0], dk[l][1]);
      else
        k_spmm_csr<false><<<(N + 3) / 4, 256, 0, stream>>>(RO, CV, A, nullptr, B, dk[l][0], dk[l][1]);
      if (l < 2)
        k_gemm_mfma<HID, true><<<gemm_blocks, 256, 0, stream>>>(B, Whs[l], Wls[l], bs[l], A, AbfArg, out, HID * (l + 1));
      else
        k_gemm_mfma<IEMB, false><<<gemm_blocks, 256, 0, stream>>>(B, Whs[2], Wls[2], bs[2], nullptr, nullptr, out, 3 * HID);
    } else {
      k_zero<<<(N * HID / 4 + 255) / 256, 256, 0, stream>>>((float4*)B, N * HID / 4);
      k_spmm<<<NNZ / 4, 256, 0, stream>>>(g_rows, g_cols, g_vals, A, B);
      k_dropres<<<(N * HID) / 256, 256, 0, stream>>>(A, B, dk[l][0], dk[l][1]);
      if (l < 2)
        k_gemm<HID, true><<<gemm_blocks, 256, 0, stream>>>(B, Ws[l], bs[l], A, out, HID * (l + 1));
      else
        k_gemm<IEMB, false><<<gemm_blocks, 256, 0, stream>>>(B, Ws[2], bs[2], nullptr, out, 3 * HID);
    }
  }
}